// Round 1
// baseline (694.092 us; speedup 1.0000x reference)
//
#include <hip/hip_runtime.h>
#include <hip/hip_bf16.h>
#include <stdint.h>

typedef unsigned short u16_t;
typedef __attribute__((ext_vector_type(8))) short short8;
typedef __attribute__((ext_vector_type(4))) float f32x4;
typedef __attribute__((ext_vector_type(4))) unsigned short us4;

__device__ __forceinline__ float bf2f(u16_t u) {
  union { unsigned int i; float f; } c; c.i = ((unsigned int)u) << 16; return c.f;
}
__device__ __forceinline__ u16_t f2bf(float f) {
  union { float f; unsigned int i; } c; c.f = f;
  unsigned int x = c.i;
  unsigned int r = x + 0x7fffu + ((x >> 16) & 1u);
  return (u16_t)(r >> 16);
}

// global -> LDS direct (16B per lane). LDS dest is wave-uniform base + lane*16.
__device__ __forceinline__ void gload_lds16(const u16_t* g, u16_t* l) {
  __builtin_amdgcn_global_load_lds(
      (const __attribute__((address_space(1))) void*)g,
      (__attribute__((address_space(3))) void*)(unsigned int)(uintptr_t)l,
      16, 0, 0);
}

struct Seg {
  const u16_t* A;
  const u16_t* B;
  int boff;   // padded-row offset for conv taps
};

struct GemmArgs {
  Seg segs[27];
  int nseg;
  int K;
  int ldA, ldB;          // element leading dims (K-contiguous rows)
  long long sA, sB;      // batch strides (elements)
  int M, N;
  float alpha;
  const float* ep_scale; // per-m scale (nullptr => 1.0)
  const float* ep_bias;  // per-m bias
  float* outf;
  u16_t* outh;
  u16_t* outl;
  long long sOut;        // batch stride of output (elements)
  int ldT;               // leading dim of output layout
};

// TN GEMM: C[m,n] = sum_k A[m,k] * BT[n,k], both operands K-contiguous bf16.
// EPI 0: val=relu(acc*scale[m]+bias[m]); split hi/lo; TRANSPOSED store out[n*ldT+m]
// EPI 1: val=relu(acc+bias[m]); split hi/lo; NORMAL store out[m*ldT+n]
// EPI 2: val=acc*alpha; fp32 TRANSPOSED float4 store out[n*ldT+m]
template<int BM, int BN, int EPI, bool PADB>
__global__ __launch_bounds__(256, 2) void gemm_tn(GemmArgs args) {
  constexpr int FM = BM / 32, FN = BN / 32;
  __shared__ __align__(16) u16_t lA[4][BM][8];
  __shared__ __align__(16) u16_t lB[4][BN][8];
  const int tid = threadIdx.x;
  const int wave = tid >> 6, lane = tid & 63;
  const int lhi = lane >> 4, llo = lane & 15;
  const int wr = wave >> 1, wc = wave & 1;
  const int nt = blockIdx.x, mt = blockIdx.y, b = blockIdx.z;
  const int row0 = mt * BM, col0 = nt * BN;

  f32x4 acc[FM][FN];
  const f32x4 zero4 = {0.f, 0.f, 0.f, 0.f};
#pragma unroll
  for (int i = 0; i < FM; ++i)
#pragma unroll
    for (int j = 0; j < FN; ++j) acc[i][j] = zero4;

  constexpr int RA = BM / 64;
  constexpr int RB = BN / 64;
  u16_t* aflat = &lA[0][0][0];
  u16_t* bflat = &lB[0][0][0];

  for (int s = 0; s < args.nseg; ++s) {
    const u16_t* Ab = args.segs[s].A + (size_t)b * args.sA;
    const u16_t* Bb = args.segs[s].B + (size_t)b * args.sB;
    const int boff = args.segs[s].boff;
    for (int k0 = 0; k0 < args.K; k0 += 32) {
      __syncthreads();
#pragma unroll
      for (int r = 0; r < RA; ++r) {
        int idx = (r * 4 + wave) * 64 + lane;
        int chunk = idx / BM, m = idx % BM;
        const u16_t* src = Ab + (size_t)(row0 + m) * args.ldA + (k0 + chunk * 8);
        gload_lds16(src, aflat + (size_t)((r * 4 + wave) * 64) * 8);
      }
#pragma unroll
      for (int r = 0; r < RB; ++r) {
        int idx = (r * 4 + wave) * 64 + lane;
        int chunk = idx / BN, n = idx % BN;
        long long rowi;
        if (PADB) {
          int gn = col0 + n;
          rowi = (long long)((gn >> 6) + 1) * 66 + (gn & 63) + 1 + boff;
        } else {
          rowi = col0 + n;
        }
        const u16_t* src = Bb + (size_t)rowi * args.ldB + (k0 + chunk * 8);
        gload_lds16(src, bflat + (size_t)((r * 4 + wave) * 64) * 8);
      }
      __syncthreads();
      short8 af[FM], bfr[FN];
#pragma unroll
      for (int i = 0; i < FM; ++i)
        af[i] = *(const short8*)&lA[lhi][wr * (BM / 2) + i * 16 + llo][0];
#pragma unroll
      for (int j = 0; j < FN; ++j)
        bfr[j] = *(const short8*)&lB[lhi][wc * (BN / 2) + j * 16 + llo][0];
#pragma unroll
      for (int i = 0; i < FM; ++i)
#pragma unroll
        for (int j = 0; j < FN; ++j)
          acc[i][j] = __builtin_amdgcn_mfma_f32_16x16x32_bf16(af[i], bfr[j], acc[i][j], 0, 0, 0);
    }
  }

#pragma unroll
  for (int i = 0; i < FM; ++i) {
    int mb = row0 + wr * (BM / 2) + i * 16 + lhi * 4;
#pragma unroll
    for (int j = 0; j < FN; ++j) {
      int n = col0 + wc * (BN / 2) + j * 16 + llo;
      if (EPI == 0) {
        us4 h, l;
#pragma unroll
        for (int r2 = 0; r2 < 4; ++r2) {
          int m = mb + r2;
          float sc = args.ep_scale ? args.ep_scale[m] : 1.f;
          float vv = acc[i][j][r2] * sc + args.ep_bias[m];
          vv = vv > 0.f ? vv : 0.f;
          u16_t hh = f2bf(vv);
          h[r2] = hh;
          l[r2] = f2bf(vv - bf2f(hh));
        }
        size_t o = (size_t)b * args.sOut + (size_t)n * args.ldT + mb;
        *(us4*)(args.outh + o) = h;
        *(us4*)(args.outl + o) = l;
      } else if (EPI == 1) {
#pragma unroll
        for (int r2 = 0; r2 < 4; ++r2) {
          int m = mb + r2;
          float vv = acc[i][j][r2] + args.ep_bias[m];
          vv = vv > 0.f ? vv : 0.f;
          size_t o = (size_t)b * args.sOut + (size_t)m * args.ldT + n;
          u16_t hh = f2bf(vv);
          args.outh[o] = hh;
          args.outl[o] = f2bf(vv - bf2f(hh));
        }
      } else {
        f32x4 vv = acc[i][j] * args.alpha;
        size_t o = (size_t)b * args.sOut + (size_t)n * args.ldT + mb;
        *(f32x4*)(args.outf + o) = vv;
      }
    }
  }
}

// Row softmax over 4096, in-place fp32 + bf16 copy for PV.
__global__ __launch_bounds__(256) void softmax_k(float* S, u16_t* P) {
  const int row = blockIdx.x;
  float* Sr = S + (size_t)row * 4096;
  u16_t* Pr = P + (size_t)row * 4096;
  const int t = threadIdx.x;
  const int wave = t >> 6;
  f32x4 v[4];
  float vmax = -3.4e38f;
#pragma unroll
  for (int i = 0; i < 4; ++i) {
    v[i] = ((const f32x4*)Sr)[t + i * 256];
#pragma unroll
    for (int c = 0; c < 4; ++c) vmax = fmaxf(vmax, v[i][c]);
  }
#pragma unroll
  for (int off = 32; off; off >>= 1) vmax = fmaxf(vmax, __shfl_xor(vmax, off));
  __shared__ float red[4];
  if ((t & 63) == 0) red[wave] = vmax;
  __syncthreads();
  vmax = fmaxf(fmaxf(red[0], red[1]), fmaxf(red[2], red[3]));
  float sum = 0.f;
#pragma unroll
  for (int i = 0; i < 4; ++i)
#pragma unroll
    for (int c = 0; c < 4; ++c) { v[i][c] = __expf(v[i][c] - vmax); sum += v[i][c]; }
#pragma unroll
  for (int off = 32; off; off >>= 1) sum += __shfl_xor(sum, off);
  __shared__ float red2[4];
  if ((t & 63) == 0) red2[wave] = sum;
  __syncthreads();
  sum = red2[0] + red2[1] + red2[2] + red2[3];
  float rs = 1.0f / sum;
#pragma unroll
  for (int i = 0; i < 4; ++i) {
    f32x4 o = v[i] * rs;
    ((f32x4*)Sr)[t + i * 256] = o;
    us4 pb;
#pragma unroll
    for (int c = 0; c < 4; ++c) pb[c] = f2bf(o[c]);
    ((us4*)Pr)[t + i * 256] = pb;
  }
}

// x [2][512][4096] -> padded transposed split xT [2][4356][512] (hi/lo bf16).
__global__ __launch_bounds__(256) void xprep(const float* __restrict__ x,
                                             u16_t* __restrict__ xh, u16_t* __restrict__ xl) {
  __shared__ float tile[64][65];
  const int b = blockIdx.z, c0 = blockIdx.y * 64, n0 = blockIdx.x * 64;
  const float* xb = x + ((size_t)b * 512 + c0) * 4096 + n0;
  const int t = threadIdx.x;
  const int tr = t >> 6, tc = t & 63;
#pragma unroll
  for (int rr = 0; rr < 16; ++rr) {
    int ci = tr + rr * 4;
    tile[ci][tc] = xb[(size_t)ci * 4096 + tc];
  }
  __syncthreads();
#pragma unroll
  for (int rr = 0; rr < 16; ++rr) {
    int nj = rr * 4 + tr;
    float v = tile[tc][nj];
    size_t rp = (size_t)(blockIdx.x + 1) * 66 + nj + 1;
    size_t o = ((size_t)b * 4356 + rp) * 512 + c0 + tc;
    u16_t hh = f2bf(v);
    xh[o] = hh;
    xl[o] = f2bf(v - bf2f(hh));
  }
}

// wv1 [256][512][3][3] -> [9][256][512] hi/lo
__global__ __launch_bounds__(256) void wprep(const float* __restrict__ wv1,
                                             u16_t* __restrict__ wh, u16_t* __restrict__ wl) {
  size_t i = (size_t)blockIdx.x * 256 + threadIdx.x;
  const size_t total = 9ull * 256 * 512;
  if (i >= total) return;
  int tp = (int)(i / (256 * 512));
  int rem = (int)(i % (256 * 512));
  int o = rem / 512, c = rem % 512;
  float v = wv1[((size_t)o * 512 + c) * 9 + tp];
  u16_t hh = f2bf(v);
  wh[i] = hh;
  wl[i] = f2bf(v - bf2f(hh));
}

__global__ __launch_bounds__(256) void splitk(const float* __restrict__ s,
                                              u16_t* __restrict__ h, u16_t* __restrict__ l, int n) {
  int i = blockIdx.x * 256 + threadIdx.x;
  if (i < n) {
    float v = s[i];
    u16_t hh = f2bf(v);
    h[i] = hh;
    l[i] = f2bf(v - bf2f(hh));
  }
}

__global__ __launch_bounds__(256) void bnprep(const float* g, const float* be, const float* mu,
                                              const float* var, const float* bk,
                                              float* sA, float* sB) {
  int i = threadIdx.x;
  float s = g[i] * rsqrtf(var[i] + 1e-5f);
  sA[i] = s;
  sB[i] = (bk[i] - mu[i]) * s + be[i];
}

extern "C" void kernel_launch(void* const* d_in, const int* in_sizes, int n_in,
                              void* d_out, int out_size, void* d_ws, size_t ws_size,
                              hipStream_t stream) {
  (void)in_sizes; (void)n_in; (void)out_size; (void)ws_size;
  const float* x   = (const float*)d_in[0];
  const float* wk  = (const float*)d_in[1];
  const float* bk  = (const float*)d_in[2];
  const float* gam = (const float*)d_in[3];
  const float* bet = (const float*)d_in[4];
  const float* mu  = (const float*)d_in[5];
  const float* var = (const float*)d_in[6];
  const float* wv1 = (const float*)d_in[7];
  const float* bv1 = (const float*)d_in[8];
  const float* wv2 = (const float*)d_in[9];
  const float* bv2 = (const float*)d_in[10];

  const int B = 2;
  const size_t XT_E  = (size_t)B * 4356 * 512;
  const size_t WK_E  = 256 * 512;
  const size_t WV1_E = 9ull * 256 * 512;
  const size_t WV2_E = 256 * 256;
  const size_t FT_E  = (size_t)B * 4096 * 256;
  const size_t P_E   = (size_t)B * 4096 * 4096;

  size_t off = 0;
  auto carve = [&](size_t bytes) -> char* {
    off = (off + 255) & ~(size_t)255;
    char* p = (char*)d_ws + off;
    off += bytes;
    return p;
  };
  u16_t* xh  = (u16_t*)carve(XT_E * 2);
  u16_t* xl  = (u16_t*)carve(XT_E * 2);
  u16_t* wkh = (u16_t*)carve(WK_E * 2);
  u16_t* wkl = (u16_t*)carve(WK_E * 2);
  u16_t* w1h = (u16_t*)carve(WV1_E * 2);
  u16_t* w1l = (u16_t*)carve(WV1_E * 2);
  u16_t* w2h = (u16_t*)carve(WV2_E * 2);
  u16_t* w2l = (u16_t*)carve(WV2_E * 2);
  u16_t* fth = (u16_t*)carve(FT_E * 2);
  u16_t* ftl = (u16_t*)carve(FT_E * 2);
  u16_t* v1h = (u16_t*)carve(FT_E * 2);
  u16_t* v1l = (u16_t*)carve(FT_E * 2);
  u16_t* vh  = (u16_t*)carve(FT_E * 2);
  u16_t* vl  = (u16_t*)carve(FT_E * 2);
  u16_t* Pb  = (u16_t*)carve(P_E * 2);
  float* bnA = (float*)carve(256 * 4);
  float* bnB = (float*)carve(256 * 4);

  float* ctx = (float*)d_out;                         // [2][256][4096]
  float* sim = (float*)d_out + (size_t)B * 256 * 4096; // [2][4096][4096]

  hipMemsetAsync(xh, 0, XT_E * 2, stream);
  hipMemsetAsync(xl, 0, XT_E * 2, stream);
  bnprep<<<1, 256, 0, stream>>>(gam, bet, mu, var, bk, bnA, bnB);
  splitk<<<(int)((WK_E + 255) / 256), 256, 0, stream>>>(wk, wkh, wkl, (int)WK_E);
  splitk<<<(int)((WV2_E + 255) / 256), 256, 0, stream>>>(wv2, w2h, w2l, (int)WV2_E);
  wprep<<<(int)((WV1_E + 255) / 256), 256, 0, stream>>>(wv1, w1h, w1l);
  xprep<<<dim3(64, 8, 2), 256, 0, stream>>>(x, xh, xl);

  // feat = relu(BN(wk @ x)) -> featT [b][n][ck] split
  {
    GemmArgs a = {};
    a.segs[0] = {wkh, xh, 0}; a.segs[1] = {wkl, xh, 0}; a.segs[2] = {wkh, xl, 0};
    a.nseg = 3; a.K = 512; a.ldA = 512; a.ldB = 512;
    a.sA = 0; a.sB = (long long)4356 * 512;
    a.M = 256; a.N = 4096;
    a.ep_scale = bnA; a.ep_bias = bnB;
    a.outh = fth; a.outl = ftl; a.sOut = (long long)4096 * 256; a.ldT = 256;
    gemm_tn<64, 128, 0, true><<<dim3(32, 4, 2), 256, 0, stream>>>(a);
  }
  // S = featT @ featT^T * Ck^-0.5 -> d_out sim region (symmetric, transposed store OK)
  {
    GemmArgs a = {};
    a.segs[0] = {fth, fth, 0}; a.segs[1] = {ftl, fth, 0}; a.segs[2] = {fth, ftl, 0};
    a.nseg = 3; a.K = 256; a.ldA = 256; a.ldB = 256;
    a.sA = (long long)4096 * 256; a.sB = (long long)4096 * 256;
    a.M = 4096; a.N = 4096; a.alpha = 0.0625f;
    a.outf = sim; a.sOut = (long long)4096 * 4096; a.ldT = 4096;
    gemm_tn<128, 128, 2, false><<<dim3(32, 32, 2), 256, 0, stream>>>(a);
  }
  softmax_k<<<B * 4096, 256, 0, stream>>>(sim, Pb);
  // v1 = relu(conv3x3(x) + bv1) -> v1T [b][n][cv] split (9 taps x 3 split passes)
  {
    GemmArgs a = {};
    for (int ty = 0; ty < 3; ++ty)
      for (int tx = 0; tx < 3; ++tx) {
        int tp = ty * 3 + tx;
        int boff = (ty - 1) * 66 + (tx - 1);
        a.segs[tp * 3 + 0] = {w1h + (size_t)tp * 131072, xh, boff};
        a.segs[tp * 3 + 1] = {w1l + (size_t)tp * 131072, xh, boff};
        a.segs[tp * 3 + 2] = {w1h + (size_t)tp * 131072, xl, boff};
      }
    a.nseg = 27; a.K = 512; a.ldA = 512; a.ldB = 512;
    a.sA = 0; a.sB = (long long)4356 * 512;
    a.M = 256; a.N = 4096;
    a.ep_scale = nullptr; a.ep_bias = bv1;
    a.outh = v1h; a.outl = v1l; a.sOut = (long long)4096 * 256; a.ldT = 256;
    gemm_tn<64, 128, 0, true><<<dim3(32, 4, 2), 256, 0, stream>>>(a);
  }
  // v = relu(wv2 @ v1 + bv2) -> v [b][cv][n] split (normal layout: PV's BT operand)
  {
    GemmArgs a = {};
    a.segs[0] = {w2h, v1h, 0}; a.segs[1] = {w2l, v1h, 0}; a.segs[2] = {w2h, v1l, 0};
    a.nseg = 3; a.K = 256; a.ldA = 256; a.ldB = 256;
    a.sA = 0; a.sB = (long long)4096 * 256;
    a.M = 256; a.N = 4096;
    a.ep_bias = bv2;
    a.outh = vh; a.outl = vl; a.sOut = (long long)256 * 4096; a.ldT = 4096;
    gemm_tn<64, 128, 1, false><<<dim3(32, 4, 2), 256, 0, stream>>>(a);
  }
  // ctx[c][n] = sum_m P[n][m] v[c][m]  (M=4096 rows=n, N=256 cols=c, K=4096)
  {
    GemmArgs a = {};
    a.segs[0] = {Pb, vh, 0}; a.segs[1] = {Pb, vl, 0};
    a.nseg = 2; a.K = 4096; a.ldA = 4096; a.ldB = 4096;
    a.sA = (long long)4096 * 4096; a.sB = (long long)256 * 4096;
    a.M = 4096; a.N = 256; a.alpha = 1.f;
    a.outf = ctx; a.sOut = (long long)256 * 4096; a.ldT = 4096;
    gemm_tn<128, 64, 2, false><<<dim3(4, 32, 2), 256, 0, stream>>>(a);
  }
}

// Round 2
// 583.454 us; speedup vs baseline: 1.1896x; 1.1896x over previous
//
#include <hip/hip_runtime.h>
#include <hip/hip_bf16.h>
#include <stdint.h>

typedef unsigned short u16_t;
typedef __attribute__((ext_vector_type(8))) short short8;
typedef __attribute__((ext_vector_type(4))) float f32x4;
typedef __attribute__((ext_vector_type(4))) unsigned short us4;

__device__ __forceinline__ float bf2f(u16_t u) {
  union { unsigned int i; float f; } c; c.i = ((unsigned int)u) << 16; return c.f;
}
__device__ __forceinline__ u16_t f2bf(float f) {
  union { float f; unsigned int i; } c; c.f = f;
  unsigned int x = c.i;
  unsigned int r = x + 0x7fffu + ((x >> 16) & 1u);
  return (u16_t)(r >> 16);
}

__device__ __forceinline__ void gload_lds16(const u16_t* g, u16_t* l) {
  __builtin_amdgcn_global_load_lds(
      (const __attribute__((address_space(1))) void*)g,
      (__attribute__((address_space(3))) void*)(unsigned int)(uintptr_t)l,
      16, 0, 0);
}

struct Seg {
  const u16_t* A;
  const u16_t* B;
  int boff;   // padded-row offset for conv taps
};

struct GemmArgs {
  Seg segs[27];
  int nseg;
  int segs_per_split;
  int K;
  int ldA, ldB;
  long long sA, sB;      // batch strides (elements)
  float alpha;
  float* outf;           // fp32 output (final or split partials)
  long long sOut;        // batch stride of output
  long long sSplit;      // split stride of output (0 => no split)
  int ldT;               // leading dim of transposed store
};

// TN GEMM: C[m,n] = sum_{segs in split} A[m,k]*BT[n,k]. fp32 transposed store:
// out[split*sSplit + b*sOut + n*ldT + m] = acc*alpha  (float4 over m)
template<int BM, int BN, bool PADB>
__global__ __launch_bounds__(256, 2) void gemm_tn(GemmArgs args) {
  constexpr int FM = BM / 32, FN = BN / 32;
  __shared__ __align__(16) u16_t lA[4][BM][8];
  __shared__ __align__(16) u16_t lB[4][BN][8];
  const int tid = threadIdx.x;
  const int wave = tid >> 6, lane = tid & 63;
  const int lhi = lane >> 4, llo = lane & 15;
  const int wr = wave >> 1, wc = wave & 1;
  const int nt = blockIdx.x, mt = blockIdx.y;
  const int z = blockIdx.z;
  const int b = z & 1, split = z >> 1;
  const int row0 = mt * BM, col0 = nt * BN;

  f32x4 acc[FM][FN];
  const f32x4 zero4 = {0.f, 0.f, 0.f, 0.f};
#pragma unroll
  for (int i = 0; i < FM; ++i)
#pragma unroll
    for (int j = 0; j < FN; ++j) acc[i][j] = zero4;

  constexpr int RA = BM / 64;
  constexpr int RB = BN / 64;
  u16_t* aflat = &lA[0][0][0];
  u16_t* bflat = &lB[0][0][0];

  const int s0 = split * args.segs_per_split;
  int s1 = s0 + args.segs_per_split;
  if (s1 > args.nseg) s1 = args.nseg;

  for (int s = s0; s < s1; ++s) {
    const u16_t* Ab = args.segs[s].A + (size_t)b * args.sA;
    const u16_t* Bb = args.segs[s].B + (size_t)b * args.sB;
    const int boff = args.segs[s].boff;
    for (int k0 = 0; k0 < args.K; k0 += 32) {
      __syncthreads();
#pragma unroll
      for (int r = 0; r < RA; ++r) {
        int idx = (r * 4 + wave) * 64 + lane;
        int chunk = idx / BM, m = idx % BM;
        const u16_t* src = Ab + (size_t)(row0 + m) * args.ldA + (k0 + chunk * 8);
        gload_lds16(src, aflat + (size_t)((r * 4 + wave) * 64) * 8);
      }
#pragma unroll
      for (int r = 0; r < RB; ++r) {
        int idx = (r * 4 + wave) * 64 + lane;
        int chunk = idx / BN, n = idx % BN;
        long long rowi;
        if (PADB) {
          int gn = col0 + n;
          rowi = (long long)((gn >> 6) + 1) * 66 + (gn & 63) + 1 + boff;
        } else {
          rowi = col0 + n;
        }
        const u16_t* src = Bb + (size_t)rowi * args.ldB + (k0 + chunk * 8);
        gload_lds16(src, bflat + (size_t)((r * 4 + wave) * 64) * 8);
      }
      __syncthreads();
      short8 af[FM], bfr[FN];
#pragma unroll
      for (int i = 0; i < FM; ++i)
        af[i] = *(const short8*)&lA[lhi][wr * (BM / 2) + i * 16 + llo][0];
#pragma unroll
      for (int j = 0; j < FN; ++j)
        bfr[j] = *(const short8*)&lB[lhi][wc * (BN / 2) + j * 16 + llo][0];
#pragma unroll
      for (int i = 0; i < FM; ++i)
#pragma unroll
        for (int j = 0; j < FN; ++j)
          acc[i][j] = __builtin_amdgcn_mfma_f32_16x16x32_bf16(af[i], bfr[j], acc[i][j], 0, 0, 0);
    }
  }

  float* outp = args.outf + (size_t)split * args.sSplit + (size_t)b * args.sOut;
#pragma unroll
  for (int i = 0; i < FM; ++i) {
    int mb = row0 + wr * (BM / 2) + i * 16 + lhi * 4;
#pragma unroll
    for (int j = 0; j < FN; ++j) {
      int n = col0 + wc * (BN / 2) + j * 16 + llo;
      f32x4 vv = acc[i][j] * args.alpha;
      *(f32x4*)(outp + (size_t)n * args.ldT + mb) = vv;
    }
  }
}

// Sum ns split-partials; apply (optional scale)*v+bias, relu; split-store bf16 hi/lo.
// PER_COL: bias/scale indexed by (i % LDT). else by ((i / LDT) % 256).
template<int LDT, bool PER_COL>
__global__ __launch_bounds__(256) void reduce_split(
    const float* __restrict__ part, long long sSplit, int ns,
    const float* __restrict__ scale, const float* __restrict__ bias,
    u16_t* __restrict__ oh, u16_t* __restrict__ ol, long long total) {
  long long i = ((long long)blockIdx.x * 256 + threadIdx.x) * 4;
  if (i >= total) return;
  f32x4 s = *(const f32x4*)(part + i);
  for (int p = 1; p < ns; ++p) s += *(const f32x4*)(part + (size_t)p * sSplit + i);
  f32x4 v;
  if (PER_COL) {
    int c = (int)(i & (LDT - 1));
    f32x4 bi = *(const f32x4*)(bias + c);
    if (scale) { f32x4 sc = *(const f32x4*)(scale + c); v = s * sc + bi; }
    else v = s + bi;
  } else {
    int r = (int)((i / LDT) & 255);
    float bi = bias[r];
    v = s + bi;
  }
  us4 h, l;
#pragma unroll
  for (int c2 = 0; c2 < 4; ++c2) {
    float vv = v[c2] > 0.f ? v[c2] : 0.f;
    u16_t hh = f2bf(vv);
    h[c2] = hh;
    l[c2] = f2bf(vv - bf2f(hh));
  }
  *(us4*)(oh + i) = h;
  *(us4*)(ol + i) = l;
}

__global__ __launch_bounds__(256) void reduce_split_f32(
    const float* __restrict__ part, long long sSplit, int ns,
    float* __restrict__ out, long long total) {
  long long i = ((long long)blockIdx.x * 256 + threadIdx.x) * 4;
  if (i >= total) return;
  f32x4 s = *(const f32x4*)(part + i);
  for (int p = 1; p < ns; ++p) s += *(const f32x4*)(part + (size_t)p * sSplit + i);
  *(f32x4*)(out + i) = s;
}

// Row softmax over 4096, in-place fp32 + bf16 copy for PV.
__global__ __launch_bounds__(256) void softmax_k(float* S, u16_t* P) {
  const int row = blockIdx.x;
  float* Sr = S + (size_t)row * 4096;
  u16_t* Pr = P + (size_t)row * 4096;
  const int t = threadIdx.x;
  const int wave = t >> 6;
  f32x4 v[4];
  float vmax = -3.4e38f;
#pragma unroll
  for (int i = 0; i < 4; ++i) {
    v[i] = ((const f32x4*)Sr)[t + i * 256];
#pragma unroll
    for (int c = 0; c < 4; ++c) vmax = fmaxf(vmax, v[i][c]);
  }
#pragma unroll
  for (int off = 32; off; off >>= 1) vmax = fmaxf(vmax, __shfl_xor(vmax, off));
  __shared__ float red[4];
  if ((t & 63) == 0) red[wave] = vmax;
  __syncthreads();
  vmax = fmaxf(fmaxf(red[0], red[1]), fmaxf(red[2], red[3]));
  float sum = 0.f;
#pragma unroll
  for (int i = 0; i < 4; ++i)
#pragma unroll
    for (int c = 0; c < 4; ++c) { v[i][c] = __expf(v[i][c] - vmax); sum += v[i][c]; }
#pragma unroll
  for (int off = 32; off; off >>= 1) sum += __shfl_xor(sum, off);
  __shared__ float red2[4];
  if ((t & 63) == 0) red2[wave] = sum;
  __syncthreads();
  sum = red2[0] + red2[1] + red2[2] + red2[3];
  float rs = 1.0f / sum;
#pragma unroll
  for (int i = 0; i < 4; ++i) {
    f32x4 o = v[i] * rs;
    ((f32x4*)Sr)[t + i * 256] = o;
    us4 pb;
#pragma unroll
    for (int c = 0; c < 4; ++c) pb[c] = f2bf(o[c]);
    ((us4*)Pr)[t + i * 256] = pb;
  }
}

// x [2][512][4096] -> padded transposed split xT [2][4356][512] (hi/lo bf16).
__global__ __launch_bounds__(256) void xprep(const float* __restrict__ x,
                                             u16_t* __restrict__ xh, u16_t* __restrict__ xl) {
  __shared__ float tile[64][65];
  const int b = blockIdx.z, c0 = blockIdx.y * 64, n0 = blockIdx.x * 64;
  const float* xb = x + ((size_t)b * 512 + c0) * 4096 + n0;
  const int t = threadIdx.x;
  const int tr = t >> 6, tc = t & 63;
#pragma unroll
  for (int rr = 0; rr < 16; ++rr) {
    int ci = tr + rr * 4;
    tile[ci][tc] = xb[(size_t)ci * 4096 + tc];
  }
  __syncthreads();
#pragma unroll
  for (int rr = 0; rr < 16; ++rr) {
    int nj = rr * 4 + tr;
    float v = tile[tc][nj];
    size_t rp = (size_t)(blockIdx.x + 1) * 66 + nj + 1;
    size_t o = ((size_t)b * 4356 + rp) * 512 + c0 + tc;
    u16_t hh = f2bf(v);
    xh[o] = hh;
    xl[o] = f2bf(v - bf2f(hh));
  }
}

// wv1 [256][512][3][3] -> [9][256][512] hi/lo
__global__ __launch_bounds__(256) void wprep(const float* __restrict__ wv1,
                                             u16_t* __restrict__ wh, u16_t* __restrict__ wl) {
  size_t i = (size_t)blockIdx.x * 256 + threadIdx.x;
  const size_t total = 9ull * 256 * 512;
  if (i >= total) return;
  int tp = (int)(i / (256 * 512));
  int rem = (int)(i % (256 * 512));
  int o = rem / 512, c = rem % 512;
  float v = wv1[((size_t)o * 512 + c) * 9 + tp];
  u16_t hh = f2bf(v);
  wh[i] = hh;
  wl[i] = f2bf(v - bf2f(hh));
}

__global__ __launch_bounds__(256) void splitk(const float* __restrict__ s,
                                              u16_t* __restrict__ h, u16_t* __restrict__ l, int n) {
  int i = blockIdx.x * 256 + threadIdx.x;
  if (i < n) {
    float v = s[i];
    u16_t hh = f2bf(v);
    h[i] = hh;
    l[i] = f2bf(v - bf2f(hh));
  }
}

__global__ __launch_bounds__(256) void bnprep(const float* g, const float* be, const float* mu,
                                              const float* var, const float* bk,
                                              float* sA, float* sB) {
  int i = threadIdx.x;
  float s = g[i] * rsqrtf(var[i] + 1e-5f);
  sA[i] = s;
  sB[i] = (bk[i] - mu[i]) * s + be[i];
}

extern "C" void kernel_launch(void* const* d_in, const int* in_sizes, int n_in,
                              void* d_out, int out_size, void* d_ws, size_t ws_size,
                              hipStream_t stream) {
  (void)in_sizes; (void)n_in; (void)out_size; (void)ws_size;
  const float* x   = (const float*)d_in[0];
  const float* wk  = (const float*)d_in[1];
  const float* bk  = (const float*)d_in[2];
  const float* gam = (const float*)d_in[3];
  const float* bet = (const float*)d_in[4];
  const float* mu  = (const float*)d_in[5];
  const float* var = (const float*)d_in[6];
  const float* wv1 = (const float*)d_in[7];
  const float* bv1 = (const float*)d_in[8];
  const float* wv2 = (const float*)d_in[9];
  const float* bv2 = (const float*)d_in[10];

  const int B = 2;
  const size_t XT_E  = (size_t)B * 4356 * 512;
  const size_t WK_E  = 256 * 512;
  const size_t WV1_E = 9ull * 256 * 512;
  const size_t WV2_E = 256 * 256;
  const size_t FT_E  = (size_t)B * 4096 * 256;   // 2,097,152
  const size_t P_E   = (size_t)B * 4096 * 4096;

  size_t off = 0;
  auto carve = [&](size_t bytes) -> char* {
    off = (off + 255) & ~(size_t)255;
    char* p = (char*)d_ws + off;
    off += bytes;
    return p;
  };
  u16_t* xh  = (u16_t*)carve(XT_E * 2);
  u16_t* xl  = (u16_t*)carve(XT_E * 2);
  u16_t* wkh = (u16_t*)carve(WK_E * 2);
  u16_t* wkl = (u16_t*)carve(WK_E * 2);
  u16_t* w1h = (u16_t*)carve(WV1_E * 2);
  u16_t* w1l = (u16_t*)carve(WV1_E * 2);
  u16_t* w2h = (u16_t*)carve(WV2_E * 2);
  u16_t* w2l = (u16_t*)carve(WV2_E * 2);
  u16_t* fth = (u16_t*)carve(FT_E * 2);
  u16_t* ftl = (u16_t*)carve(FT_E * 2);
  u16_t* v1h = (u16_t*)carve(FT_E * 2);
  u16_t* v1l = (u16_t*)carve(FT_E * 2);
  u16_t* vh  = (u16_t*)carve(FT_E * 2);
  u16_t* vl  = (u16_t*)carve(FT_E * 2);
  u16_t* Pb  = (u16_t*)carve(P_E * 2);
  float* bnA = (float*)carve(256 * 4);
  float* bnB = (float*)carve(256 * 4);

  // Aliased scratch (lifetimes verified):
  //  big_part: lives in Pb's region; used by feat/conv/wv2 partials, all of
  //            which complete before softmax writes Pb.   max 7*8.39MB < 64MB
  //  pv_part : lives at ws start (xh/xl region, dead after conv GEMM). 33.5MB < 35.6MB
  float* big_part = (float*)Pb;
  float* pv_part  = (float*)d_ws;

  float* ctx = (float*)d_out;                          // [2][256][4096]
  float* sim = (float*)d_out + (size_t)B * 256 * 4096; // [2][4096][4096]

  const long long FT_LL = (long long)FT_E;             // 2,097,152

  hipMemsetAsync(xh, 0, XT_E * 2, stream);
  hipMemsetAsync(xl, 0, XT_E * 2, stream);
  bnprep<<<1, 256, 0, stream>>>(gam, bet, mu, var, bk, bnA, bnB);
  splitk<<<(int)((WK_E + 255) / 256), 256, 0, stream>>>(wk, wkh, wkl, (int)WK_E);
  splitk<<<(int)((WV2_E + 255) / 256), 256, 0, stream>>>(wv2, w2h, w2l, (int)WV2_E);
  wprep<<<(int)((WV1_E + 255) / 256), 256, 0, stream>>>(wv1, w1h, w1l);
  xprep<<<dim3(64, 8, 2), 256, 0, stream>>>(x, xh, xl);

  // ---- feat = relu(BN(wk @ x)): 6 splits (3 passes x 2 K-halves), K=256 each
  {
    GemmArgs a = {};
    a.segs[0] = {wkh,       xh,       0};
    a.segs[1] = {wkh + 256, xh + 256, 0};
    a.segs[2] = {wkl,       xh,       0};
    a.segs[3] = {wkl + 256, xh + 256, 0};
    a.segs[4] = {wkh,       xl,       0};
    a.segs[5] = {wkl + 0,   xl + 0,   0};  // placeholder fixed below
    a.segs[5] = {wkh + 256, xl + 256, 0};
    a.nseg = 6; a.segs_per_split = 1; a.K = 256; a.ldA = 512; a.ldB = 512;
    a.sA = 0; a.sB = (long long)4356 * 512; a.alpha = 1.f;
    a.outf = big_part; a.sOut = FT_LL / 2 * 0 + (long long)4096 * 256;
    a.sSplit = FT_LL; a.ldT = 256;
    gemm_tn<64, 128, true><<<dim3(32, 4, 12), 256, 0, stream>>>(a);
    reduce_split<256, true><<<2048, 256, 0, stream>>>(big_part, FT_LL, 6, bnA, bnB, fth, ftl, FT_LL);
  }
  // ---- QK:  S = featT @ featT^T * Ck^-0.5  (symmetric -> transposed store OK)
  {
    GemmArgs a = {};
    a.segs[0] = {fth, fth, 0}; a.segs[1] = {ftl, fth, 0}; a.segs[2] = {fth, ftl, 0};
    a.nseg = 3; a.segs_per_split = 3; a.K = 256; a.ldA = 256; a.ldB = 256;
    a.sA = (long long)4096 * 256; a.sB = (long long)4096 * 256; a.alpha = 0.0625f;
    a.outf = sim; a.sOut = (long long)4096 * 4096; a.sSplit = 0; a.ldT = 4096;
    gemm_tn<128, 128, false><<<dim3(32, 32, 2), 256, 0, stream>>>(a);
  }
  // ---- conv3x3 + bias + relu -> v1T: 27 segs (9 taps x 3 passes), 7 splits
  {
    GemmArgs a = {};
    for (int ty = 0; ty < 3; ++ty)
      for (int tx = 0; tx < 3; ++tx) {
        int tp = ty * 3 + tx;
        int boff = (ty - 1) * 66 + (tx - 1);
        a.segs[tp * 3 + 0] = {w1h + (size_t)tp * 131072, xh, boff};
        a.segs[tp * 3 + 1] = {w1l + (size_t)tp * 131072, xh, boff};
        a.segs[tp * 3 + 2] = {w1h + (size_t)tp * 131072, xl, boff};
      }
    a.nseg = 27; a.segs_per_split = 4; a.K = 512; a.ldA = 512; a.ldB = 512;
    a.sA = 0; a.sB = (long long)4356 * 512; a.alpha = 1.f;
    a.outf = big_part; a.sOut = (long long)4096 * 256; a.sSplit = FT_LL; a.ldT = 256;
    gemm_tn<64, 128, true><<<dim3(32, 4, 14), 256, 0, stream>>>(a);
    reduce_split<256, true><<<2048, 256, 0, stream>>>(big_part, FT_LL, 7, nullptr, bv1, v1h, v1l, FT_LL);
  }
  // ---- v = relu(wv2 @ v1 + bv2), flipped: M=4096 (A=v1T), N=256 (B=w2)
  //      transposed store -> partial [b][c][n]; reduce adds bv2[c] (per-row)
  {
    GemmArgs a = {};
    a.segs[0] = {v1h, w2h, 0}; a.segs[1] = {v1l, w2h, 0}; a.segs[2] = {v1h, w2l, 0};
    a.nseg = 3; a.segs_per_split = 1; a.K = 256; a.ldA = 256; a.ldB = 256;
    a.sA = (long long)4096 * 256; a.sB = 0; a.alpha = 1.f;
    a.outf = big_part; a.sOut = (long long)256 * 4096; a.sSplit = FT_LL; a.ldT = 4096;
    gemm_tn<128, 64, false><<<dim3(4, 32, 6), 256, 0, stream>>>(a);
    reduce_split<4096, false><<<2048, 256, 0, stream>>>(big_part, FT_LL, 3, nullptr, bv2, vh, vl, FT_LL);
  }
  softmax_k<<<B * 4096, 256, 0, stream>>>(sim, Pb);
  // ---- ctx = P @ v^T: M=4096(n) N=256(c) K=4096, 4 K-quarter splits x 2 segs
  {
    GemmArgs a = {};
    for (int q = 0; q < 4; ++q) {
      a.segs[2 * q + 0] = {Pb + (size_t)q * 1024, vh + (size_t)q * 1024, 0};
      a.segs[2 * q + 1] = {Pb + (size_t)q * 1024, vl + (size_t)q * 1024, 0};
    }
    a.nseg = 8; a.segs_per_split = 2; a.K = 1024; a.ldA = 4096; a.ldB = 4096;
    a.sA = (long long)4096 * 4096; a.sB = (long long)256 * 4096; a.alpha = 1.f;
    a.outf = pv_part; a.sOut = (long long)256 * 4096; a.sSplit = FT_LL; a.ldT = 4096;
    gemm_tn<128, 64, false><<<dim3(4, 32, 8), 256, 0, stream>>>(a);
    reduce_split_f32<<<2048, 256, 0, stream>>>(pv_part, FT_LL, 4, ctx, FT_LL);
  }
}

// Round 3
// 401.236 us; speedup vs baseline: 1.7299x; 1.4541x over previous
//
#include <hip/hip_runtime.h>
#include <hip/hip_bf16.h>
#include <stdint.h>

typedef unsigned short u16_t;
typedef __attribute__((ext_vector_type(8))) short short8;
typedef __attribute__((ext_vector_type(4))) float f32x4;
typedef __attribute__((ext_vector_type(4))) unsigned short us4;

__device__ __forceinline__ float bf2f(u16_t u) {
  union { unsigned int i; float f; } c; c.i = ((unsigned int)u) << 16; return c.f;
}
__device__ __forceinline__ u16_t f2bf(float f) {
  union { float f; unsigned int i; } c; c.f = f;
  unsigned int x = c.i;
  unsigned int r = x + 0x7fffu + ((x >> 16) & 1u);
  return (u16_t)(r >> 16);
}

__device__ __forceinline__ void gload_lds16(const u16_t* g, u16_t* l) {
  __builtin_amdgcn_global_load_lds(
      (const __attribute__((address_space(1))) void*)g,
      (__attribute__((address_space(3))) void*)(unsigned int)(uintptr_t)l,
      16, 0, 0);
}

struct Seg {
  const u16_t* Ah;
  const u16_t* Al;
  const u16_t* Bh;
  const u16_t* Bl;
  int boff;   // padded-row offset for conv taps
};

struct GemmArgs {
  Seg segs[9];
  int nseg;
  int segs_per_split;
  int K;                 // K per seg
  int ldA, ldB;
  long long sA, sB;      // batch strides (elements)
  float alpha;
  float* outf;           // fp32 output (final or split partials)
  long long sOut;
  long long sSplit;
  int ldT;
};

// Fused-split TN GEMM. MODE 0: acc += Ah*Bh + Al*Bh + Ah*Bl (emulated fp32).
// MODE 1: acc += Ah*Bh + Ah*Bl (A exact bf16, B split).
// fp32 transposed store: out[split*sSplit + b*sOut + n*ldT + m] (float4 over m)
template<int BM, int BN, int MODE, bool PADB>
__global__ __launch_bounds__(256, 2) void gemm_tn(GemmArgs args) {
  constexpr int FM = BM / 32, FN = BN / 32;
  __shared__ __align__(16) u16_t lAh[4][BM][8];
  __shared__ __align__(16) u16_t lAl[4][BM][8];
  __shared__ __align__(16) u16_t lBh[4][BN][8];
  __shared__ __align__(16) u16_t lBl[4][BN][8];
  const int tid = threadIdx.x;
  const int wave = tid >> 6, lane = tid & 63;
  const int lhi = lane >> 4, llo = lane & 15;
  const int wr = wave >> 1, wc = wave & 1;
  const int nt = blockIdx.x, mt = blockIdx.y;
  const int z = blockIdx.z;
  const int b = z & 1, split = z >> 1;
  const int row0 = mt * BM, col0 = nt * BN;

  f32x4 acc[FM][FN];
  const f32x4 zero4 = {0.f, 0.f, 0.f, 0.f};
#pragma unroll
  for (int i = 0; i < FM; ++i)
#pragma unroll
    for (int j = 0; j < FN; ++j) acc[i][j] = zero4;

  constexpr int RA = BM / 64;
  constexpr int RB = BN / 64;
  u16_t* aflat_h = &lAh[0][0][0];
  u16_t* aflat_l = &lAl[0][0][0];
  u16_t* bflat_h = &lBh[0][0][0];
  u16_t* bflat_l = &lBl[0][0][0];

  const int s0 = split * args.segs_per_split;
  int s1 = s0 + args.segs_per_split;
  if (s1 > args.nseg) s1 = args.nseg;

  for (int s = s0; s < s1; ++s) {
    const u16_t* Abh = args.segs[s].Ah + (size_t)b * args.sA;
    const u16_t* Abl = args.segs[s].Al + (size_t)b * args.sA;
    const u16_t* Bbh = args.segs[s].Bh + (size_t)b * args.sB;
    const u16_t* Bbl = args.segs[s].Bl + (size_t)b * args.sB;
    const int boff = args.segs[s].boff;
    for (int k0 = 0; k0 < args.K; k0 += 32) {
      __syncthreads();
#pragma unroll
      for (int r = 0; r < RA; ++r) {
        int idx = (r * 4 + wave) * 64 + lane;
        int chunk = idx / BM, m = idx % BM;
        size_t goff = (size_t)(row0 + m) * args.ldA + (k0 + chunk * 8);
        u16_t* dsth = aflat_h + (size_t)((r * 4 + wave) * 64) * 8;
        gload_lds16(Abh + goff, dsth);
        if (MODE == 0) {
          u16_t* dstl = aflat_l + (size_t)((r * 4 + wave) * 64) * 8;
          gload_lds16(Abl + goff, dstl);
        }
      }
#pragma unroll
      for (int r = 0; r < RB; ++r) {
        int idx = (r * 4 + wave) * 64 + lane;
        int chunk = idx / BN, n = idx % BN;
        long long rowi;
        if (PADB) {
          int gn = col0 + n;
          rowi = (long long)((gn >> 6) + 1) * 66 + (gn & 63) + 1 + boff;
        } else {
          rowi = col0 + n;
        }
        size_t goff = (size_t)rowi * args.ldB + (k0 + chunk * 8);
        gload_lds16(Bbh + goff, bflat_h + (size_t)((r * 4 + wave) * 64) * 8);
        gload_lds16(Bbl + goff, bflat_l + (size_t)((r * 4 + wave) * 64) * 8);
      }
      __syncthreads();
      short8 afh[FM], afl[FM], bfh[FN], bfl[FN];
#pragma unroll
      for (int i = 0; i < FM; ++i) {
        afh[i] = *(const short8*)&lAh[lhi][wr * (BM / 2) + i * 16 + llo][0];
        if (MODE == 0)
          afl[i] = *(const short8*)&lAl[lhi][wr * (BM / 2) + i * 16 + llo][0];
      }
#pragma unroll
      for (int j = 0; j < FN; ++j) {
        bfh[j] = *(const short8*)&lBh[lhi][wc * (BN / 2) + j * 16 + llo][0];
        bfl[j] = *(const short8*)&lBl[lhi][wc * (BN / 2) + j * 16 + llo][0];
      }
#pragma unroll
      for (int i = 0; i < FM; ++i)
#pragma unroll
        for (int j = 0; j < FN; ++j) {
          f32x4 t = acc[i][j];
          t = __builtin_amdgcn_mfma_f32_16x16x32_bf16(afh[i], bfl[j], t, 0, 0, 0);
          if (MODE == 0)
            t = __builtin_amdgcn_mfma_f32_16x16x32_bf16(afl[i], bfh[j], t, 0, 0, 0);
          t = __builtin_amdgcn_mfma_f32_16x16x32_bf16(afh[i], bfh[j], t, 0, 0, 0);
          acc[i][j] = t;
        }
    }
  }

  float* outp = args.outf + (size_t)split * args.sSplit + (size_t)b * args.sOut;
#pragma unroll
  for (int i = 0; i < FM; ++i) {
    int mb = row0 + wr * (BM / 2) + i * 16 + lhi * 4;
#pragma unroll
    for (int j = 0; j < FN; ++j) {
      int n = col0 + wc * (BN / 2) + j * 16 + llo;
      f32x4 vv = acc[i][j] * args.alpha;
      *(f32x4*)(outp + (size_t)n * args.ldT + mb) = vv;
    }
  }
}

// Sum ns split-partials; apply (optional scale)*v+bias, relu; split-store bf16 hi/lo.
template<int LDT, bool PER_COL>
__global__ __launch_bounds__(256) void reduce_split(
    const float* __restrict__ part, long long sSplit, int ns,
    const float* __restrict__ scale, const float* __restrict__ bias,
    u16_t* __restrict__ oh, u16_t* __restrict__ ol, long long total) {
  long long i = ((long long)blockIdx.x * 256 + threadIdx.x) * 4;
  if (i >= total) return;
  f32x4 s = *(const f32x4*)(part + i);
  for (int p = 1; p < ns; ++p) s += *(const f32x4*)(part + (size_t)p * sSplit + i);
  f32x4 v;
  if (PER_COL) {
    int c = (int)(i & (LDT - 1));
    f32x4 bi = *(const f32x4*)(bias + c);
    if (scale) { f32x4 sc = *(const f32x4*)(scale + c); v = s * sc + bi; }
    else v = s + bi;
  } else {
    int r = (int)((i / LDT) & 255);
    float bi = bias[r];
    v = s + bi;
  }
  us4 h, l;
#pragma unroll
  for (int c2 = 0; c2 < 4; ++c2) {
    float vv = v[c2] > 0.f ? v[c2] : 0.f;
    u16_t hh = f2bf(vv);
    h[c2] = hh;
    l[c2] = f2bf(vv - bf2f(hh));
  }
  *(us4*)(oh + i) = h;
  *(us4*)(ol + i) = l;
}

__global__ __launch_bounds__(256) void reduce_split_f32(
    const float* __restrict__ part, long long sSplit, int ns,
    float* __restrict__ out, long long total) {
  long long i = ((long long)blockIdx.x * 256 + threadIdx.x) * 4;
  if (i >= total) return;
  f32x4 s = *(const f32x4*)(part + i);
  for (int p = 1; p < ns; ++p) s += *(const f32x4*)(part + (size_t)p * sSplit + i);
  *(f32x4*)(out + i) = s;
}

// Row softmax over 4096, in-place fp32 + bf16 copy for PV.
__global__ __launch_bounds__(256) void softmax_k(float* S, u16_t* P) {
  const int row = blockIdx.x;
  float* Sr = S + (size_t)row * 4096;
  u16_t* Pr = P + (size_t)row * 4096;
  const int t = threadIdx.x;
  const int wave = t >> 6;
  f32x4 v[4];
  float vmax = -3.4e38f;
#pragma unroll
  for (int i = 0; i < 4; ++i) {
    v[i] = ((const f32x4*)Sr)[t + i * 256];
#pragma unroll
    for (int c = 0; c < 4; ++c) vmax = fmaxf(vmax, v[i][c]);
  }
#pragma unroll
  for (int off = 32; off; off >>= 1) vmax = fmaxf(vmax, __shfl_xor(vmax, off));
  __shared__ float red[4];
  if ((t & 63) == 0) red[wave] = vmax;
  __syncthreads();
  vmax = fmaxf(fmaxf(red[0], red[1]), fmaxf(red[2], red[3]));
  float sum = 0.f;
#pragma unroll
  for (int i = 0; i < 4; ++i)
#pragma unroll
    for (int c = 0; c < 4; ++c) { v[i][c] = __expf(v[i][c] - vmax); sum += v[i][c]; }
#pragma unroll
  for (int off = 32; off; off >>= 1) sum += __shfl_xor(sum, off);
  __shared__ float red2[4];
  if ((t & 63) == 0) red2[wave] = sum;
  __syncthreads();
  sum = red2[0] + red2[1] + red2[2] + red2[3];
  float rs = 1.0f / sum;
#pragma unroll
  for (int i = 0; i < 4; ++i) {
    f32x4 o = v[i] * rs;
    ((f32x4*)Sr)[t + i * 256] = o;
    us4 pb;
#pragma unroll
    for (int c = 0; c < 4; ++c) pb[c] = f2bf(o[c]);
    ((us4*)Pr)[t + i * 256] = pb;
  }
}

// x [2][512][4096] -> padded transposed split xT [2][4356][512] (hi/lo bf16).
__global__ __launch_bounds__(256) void xprep(const float* __restrict__ x,
                                             u16_t* __restrict__ xh, u16_t* __restrict__ xl) {
  __shared__ float tile[64][65];
  const int b = blockIdx.z, c0 = blockIdx.y * 64, n0 = blockIdx.x * 64;
  const float* xb = x + ((size_t)b * 512 + c0) * 4096 + n0;
  const int t = threadIdx.x;
  const int tr = t >> 6, tc = t & 63;
#pragma unroll
  for (int rr = 0; rr < 16; ++rr) {
    int ci = tr + rr * 4;
    tile[ci][tc] = xb[(size_t)ci * 4096 + tc];
  }
  __syncthreads();
#pragma unroll
  for (int rr = 0; rr < 16; ++rr) {
    int nj = rr * 4 + tr;
    float v = tile[tc][nj];
    size_t rp = (size_t)(blockIdx.x + 1) * 66 + nj + 1;
    size_t o = ((size_t)b * 4356 + rp) * 512 + c0 + tc;
    u16_t hh = f2bf(v);
    xh[o] = hh;
    xl[o] = f2bf(v - bf2f(hh));
  }
}

// wv1 [256][512][3][3] -> [9][256][512] hi/lo
__global__ __launch_bounds__(256) void wprep(const float* __restrict__ wv1,
                                             u16_t* __restrict__ wh, u16_t* __restrict__ wl) {
  size_t i = (size_t)blockIdx.x * 256 + threadIdx.x;
  const size_t total = 9ull * 256 * 512;
  if (i >= total) return;
  int tp = (int)(i / (256 * 512));
  int rem = (int)(i % (256 * 512));
  int o = rem / 512, c = rem % 512;
  float v = wv1[((size_t)o * 512 + c) * 9 + tp];
  u16_t hh = f2bf(v);
  wh[i] = hh;
  wl[i] = f2bf(v - bf2f(hh));
}

__global__ __launch_bounds__(256) void splitk(const float* __restrict__ s,
                                              u16_t* __restrict__ h, u16_t* __restrict__ l, int n) {
  int i = blockIdx.x * 256 + threadIdx.x;
  if (i < n) {
    float v = s[i];
    u16_t hh = f2bf(v);
    h[i] = hh;
    l[i] = f2bf(v - bf2f(hh));
  }
}

__global__ __launch_bounds__(256) void bnprep(const float* g, const float* be, const float* mu,
                                              const float* var, const float* bk,
                                              float* sA, float* sB) {
  int i = threadIdx.x;
  float s = g[i] * rsqrtf(var[i] + 1e-5f);
  sA[i] = s;
  sB[i] = (bk[i] - mu[i]) * s + be[i];
}

extern "C" void kernel_launch(void* const* d_in, const int* in_sizes, int n_in,
                              void* d_out, int out_size, void* d_ws, size_t ws_size,
                              hipStream_t stream) {
  (void)in_sizes; (void)n_in; (void)out_size; (void)ws_size;
  const float* x   = (const float*)d_in[0];
  const float* wk  = (const float*)d_in[1];
  const float* bk  = (const float*)d_in[2];
  const float* gam = (const float*)d_in[3];
  const float* bet = (const float*)d_in[4];
  const float* mu  = (const float*)d_in[5];
  const float* var = (const float*)d_in[6];
  const float* wv1 = (const float*)d_in[7];
  const float* bv1 = (const float*)d_in[8];
  const float* wv2 = (const float*)d_in[9];
  const float* bv2 = (const float*)d_in[10];

  const int B = 2;
  const size_t XT_E  = (size_t)B * 4356 * 512;
  const size_t WK_E  = 256 * 512;
  const size_t WV1_E = 9ull * 256 * 512;
  const size_t WV2_E = 256 * 256;
  const size_t FT_E  = (size_t)B * 4096 * 256;   // 2,097,152
  const size_t P_E   = (size_t)B * 4096 * 4096;

  size_t off = 0;
  auto carve = [&](size_t bytes) -> char* {
    off = (off + 255) & ~(size_t)255;
    char* p = (char*)d_ws + off;
    off += bytes;
    return p;
  };
  u16_t* xh  = (u16_t*)carve(XT_E * 2);
  u16_t* xl  = (u16_t*)carve(XT_E * 2);
  u16_t* wkh = (u16_t*)carve(WK_E * 2);
  u16_t* wkl = (u16_t*)carve(WK_E * 2);
  u16_t* w1h = (u16_t*)carve(WV1_E * 2);
  u16_t* w1l = (u16_t*)carve(WV1_E * 2);
  u16_t* w2h = (u16_t*)carve(WV2_E * 2);
  u16_t* w2l = (u16_t*)carve(WV2_E * 2);
  u16_t* fth = (u16_t*)carve(FT_E * 2);
  u16_t* ftl = (u16_t*)carve(FT_E * 2);
  u16_t* v1h = (u16_t*)carve(FT_E * 2);
  u16_t* v1l = (u16_t*)carve(FT_E * 2);
  u16_t* vh  = (u16_t*)carve(FT_E * 2);
  u16_t* vl  = (u16_t*)carve(FT_E * 2);
  u16_t* Pb  = (u16_t*)carve(P_E * 2);
  float* bnA = (float*)carve(256 * 4);
  float* bnB = (float*)carve(256 * 4);

  // Aliased scratch (lifetimes verified):
  //  big_part (Pb region): feat/conv/wv2 partials; all complete before softmax
  //            writes Pb. max 9*8.39MB = 75.5MB < 134MB.
  //  pv_part (ws start): PV partials 4*8.39MB = 33.5MB; overlaps xh/xl/wk/w1/
  //            w2/fth/ftl/part of v1h — all dead once PV runs. vh/vl start at
  //            ~40.1MB, beyond the 33.5MB partial region.
  float* big_part = (float*)Pb;
  float* pv_part  = (float*)d_ws;

  float* ctx = (float*)d_out;                          // [2][256][4096]
  float* sim = (float*)d_out + (size_t)B * 256 * 4096; // [2][4096][4096]

  const long long FT_LL = (long long)FT_E;

  hipMemsetAsync(xh, 0, XT_E * 2, stream);
  hipMemsetAsync(xl, 0, XT_E * 2, stream);
  bnprep<<<1, 256, 0, stream>>>(gam, bet, mu, var, bk, bnA, bnB);
  splitk<<<(int)((WK_E + 255) / 256), 256, 0, stream>>>(wk, wkh, wkl, (int)WK_E);
  splitk<<<(int)((WV2_E + 255) / 256), 256, 0, stream>>>(wv2, w2h, w2l, (int)WV2_E);
  wprep<<<(int)((WV1_E + 255) / 256), 256, 0, stream>>>(wv1, w1h, w1l);
  xprep<<<dim3(64, 8, 2), 256, 0, stream>>>(x, xh, xl);

  // ---- feat = relu(BN(wk @ x)): fused hi/lo, 2 K-splits of 256
  {
    GemmArgs a = {};
    a.segs[0] = {wkh,       wkl,       xh,       xl,       0};
    a.segs[1] = {wkh + 256, wkl + 256, xh + 256, xl + 256, 0};
    a.nseg = 2; a.segs_per_split = 1; a.K = 256; a.ldA = 512; a.ldB = 512;
    a.sA = 0; a.sB = (long long)4356 * 512; a.alpha = 1.f;
    a.outf = big_part; a.sOut = (long long)4096 * 256; a.sSplit = FT_LL; a.ldT = 256;
    gemm_tn<64, 128, 0, true><<<dim3(32, 4, 4), 256, 0, stream>>>(a);
    reduce_split<256, true><<<2048, 256, 0, stream>>>(big_part, FT_LL, 2, bnA, bnB, fth, ftl, FT_LL);
  }
  // ---- QK: S = featT @ featT^T * Ck^-0.5, fused, direct store (no split)
  {
    GemmArgs a = {};
    a.segs[0] = {fth, ftl, fth, ftl, 0};
    a.nseg = 1; a.segs_per_split = 1; a.K = 256; a.ldA = 256; a.ldB = 256;
    a.sA = (long long)4096 * 256; a.sB = (long long)4096 * 256; a.alpha = 0.0625f;
    a.outf = sim; a.sOut = (long long)4096 * 4096; a.sSplit = 0; a.ldT = 4096;
    gemm_tn<128, 128, 0, false><<<dim3(32, 32, 2), 256, 0, stream>>>(a);
  }
  // ---- conv3x3 + bias + relu -> v1T: 9 tap-splits, fused hi/lo
  {
    GemmArgs a = {};
    for (int ty = 0; ty < 3; ++ty)
      for (int tx = 0; tx < 3; ++tx) {
        int tp = ty * 3 + tx;
        int boff = (ty - 1) * 66 + (tx - 1);
        a.segs[tp] = {w1h + (size_t)tp * 131072, w1l + (size_t)tp * 131072, xh, xl, boff};
      }
    a.nseg = 9; a.segs_per_split = 1; a.K = 512; a.ldA = 512; a.ldB = 512;
    a.sA = 0; a.sB = (long long)4356 * 512; a.alpha = 1.f;
    a.outf = big_part; a.sOut = (long long)4096 * 256; a.sSplit = FT_LL; a.ldT = 256;
    gemm_tn<128, 128, 0, true><<<dim3(32, 2, 18), 256, 0, stream>>>(a);
    reduce_split<256, true><<<2048, 256, 0, stream>>>(big_part, FT_LL, 9, nullptr, bv1, v1h, v1l, FT_LL);
  }
  // ---- v = relu(wv2 @ v1 + bv2), flipped (M=4096, N=256), 2 K-splits of 128
  {
    GemmArgs a = {};
    a.segs[0] = {v1h,       v1l,       w2h,       w2l,       0};
    a.segs[1] = {v1h + 128, v1l + 128, w2h + 128, w2l + 128, 0};
    a.nseg = 2; a.segs_per_split = 1; a.K = 128; a.ldA = 256; a.ldB = 256;
    a.sA = (long long)4096 * 256; a.sB = 0; a.alpha = 1.f;
    a.outf = big_part; a.sOut = (long long)256 * 4096; a.sSplit = FT_LL; a.ldT = 4096;
    gemm_tn<128, 64, 0, false><<<dim3(4, 32, 4), 256, 0, stream>>>(a);
    reduce_split<4096, false><<<2048, 256, 0, stream>>>(big_part, FT_LL, 2, nullptr, bv2, vh, vl, FT_LL);
  }
  softmax_k<<<B * 4096, 256, 0, stream>>>(sim, Pb);
  // ---- ctx = P @ v^T: MODE1 (P exact, v hi/lo), 4 K-splits of 1024
  {
    GemmArgs a = {};
    for (int q = 0; q < 4; ++q)
      a.segs[q] = {Pb + (size_t)q * 1024, nullptr, vh + (size_t)q * 1024, vl + (size_t)q * 1024, 0};
    a.nseg = 4; a.segs_per_split = 1; a.K = 1024; a.ldA = 4096; a.ldB = 4096;
    a.sA = (long long)4096 * 4096; a.sB = (long long)256 * 4096; a.alpha = 1.f;
    a.outf = pv_part; a.sOut = (long long)256 * 4096; a.sSplit = FT_LL; a.ldT = 4096;
    gemm_tn<128, 128, 1, false><<<dim3(2, 32, 8), 256, 0, stream>>>(a);
    reduce_split_f32<<<2048, 256, 0, stream>>>(pv_part, FT_LL, 4, ctx, FT_LL);
  }
}

// Round 4
// 320.648 us; speedup vs baseline: 2.1647x; 1.2513x over previous
//
#include <hip/hip_runtime.h>
#include <hip/hip_bf16.h>
#include <stdint.h>

typedef unsigned short u16_t;
typedef __attribute__((ext_vector_type(8))) short short8;
typedef __attribute__((ext_vector_type(4))) float f32x4;
typedef __attribute__((ext_vector_type(4))) unsigned short us4;

__device__ __forceinline__ float bf2f(u16_t u) {
  union { unsigned int i; float f; } c; c.i = ((unsigned int)u) << 16; return c.f;
}
__device__ __forceinline__ u16_t f2bf(float f) {
  union { float f; unsigned int i; } c; c.f = f;
  unsigned int x = c.i;
  unsigned int r = x + 0x7fffu + ((x >> 16) & 1u);
  return (u16_t)(r >> 16);
}

__device__ __forceinline__ void gload_lds16(const u16_t* g, u16_t* l) {
  __builtin_amdgcn_global_load_lds(
      (const __attribute__((address_space(1))) void*)g,
      (__attribute__((address_space(3))) void*)(unsigned int)(uintptr_t)l,
      16, 0, 0);
}

struct Seg {
  const u16_t* Ah;
  const u16_t* Al;
  const u16_t* Bh;
  const u16_t* Bl;
  int boff;   // padded-row offset for conv taps
};

struct GemmArgs {
  Seg segs[9];
  int nseg;
  int segs_per_split;
  int K;                 // K per seg
  int ldA, ldB;
  long long sA, sB;      // batch strides (elements)
  float alpha;
  float* outf;           // fp32 output (final or split partials)
  long long sOut;
  long long sSplit;
  int ldT;
};

// Fused-split TN GEMM.
// MODE 0: acc += Ah*Bh + Al*Bh + Ah*Bl   (emulated fp32)
// MODE 1: acc += Ah*Bh + Ah*Bl           (A exact bf16, B split)
// MODE 2: acc += Ah*Bh                   (both bf16-rounded)
// fp32 transposed store: out[split*sSplit + b*sOut + n*ldT + m] (float4 over m)
// SYMM: blockIdx.x = upper-triangle tile index (NT=32), mirror-store transposed.
template<int BM, int BN, int MODE, bool PADB, bool SYMM>
__global__ __launch_bounds__(256, 4) void gemm_tn(GemmArgs args) {
  constexpr int FM = BM / 32, FN = BN / 32;
  __shared__ __align__(16) u16_t lAh[4][BM][8];
  __shared__ __align__(16) u16_t lAl[(MODE == 0) ? 4 : 1][BM][8];
  __shared__ __align__(16) u16_t lBh[4][BN][8];
  __shared__ __align__(16) u16_t lBl[(MODE <= 1) ? 4 : 1][BN][8];
  const int tid = threadIdx.x;
  const int wave = tid >> 6, lane = tid & 63;
  const int lhi = lane >> 4, llo = lane & 15;
  const int wr = wave >> 1, wc = wave & 1;
  int nt, mt, b, split;
  if (SYMM) {
    b = blockIdx.z; split = 0;
    int t = blockIdx.x, r = 0;
    while (t >= 32 - r) { t -= 32 - r; ++r; }
    mt = r; nt = r + t;
  } else {
    nt = blockIdx.x; mt = blockIdx.y;
    b = blockIdx.z & 1; split = blockIdx.z >> 1;
  }
  const int row0 = mt * BM, col0 = nt * BN;

  f32x4 acc[FM][FN];
  const f32x4 zero4 = {0.f, 0.f, 0.f, 0.f};
#pragma unroll
  for (int i = 0; i < FM; ++i)
#pragma unroll
    for (int j = 0; j < FN; ++j) acc[i][j] = zero4;

  constexpr int RA = BM / 64;
  constexpr int RB = BN / 64;
  u16_t* aflat_h = &lAh[0][0][0];
  u16_t* aflat_l = &lAl[0][0][0];
  u16_t* bflat_h = &lBh[0][0][0];
  u16_t* bflat_l = &lBl[0][0][0];

  const int s0 = split * args.segs_per_split;
  int s1 = s0 + args.segs_per_split;
  if (s1 > args.nseg) s1 = args.nseg;

  for (int s = s0; s < s1; ++s) {
    const u16_t* Abh = args.segs[s].Ah + (size_t)b * args.sA;
    const u16_t* Abl = args.segs[s].Al + (size_t)b * args.sA;
    const u16_t* Bbh = args.segs[s].Bh + (size_t)b * args.sB;
    const u16_t* Bbl = args.segs[s].Bl + (size_t)b * args.sB;
    const int boff = args.segs[s].boff;
    for (int k0 = 0; k0 < args.K; k0 += 32) {
      __syncthreads();
#pragma unroll
      for (int r = 0; r < RA; ++r) {
        int idx = (r * 4 + wave) * 64 + lane;
        int chunk = idx / BM, m = idx % BM;
        size_t goff = (size_t)(row0 + m) * args.ldA + (k0 + chunk * 8);
        gload_lds16(Abh + goff, aflat_h + (size_t)((r * 4 + wave) * 64) * 8);
        if (MODE == 0)
          gload_lds16(Abl + goff, aflat_l + (size_t)((r * 4 + wave) * 64) * 8);
      }
#pragma unroll
      for (int r = 0; r < RB; ++r) {
        int idx = (r * 4 + wave) * 64 + lane;
        int chunk = idx / BN, n = idx % BN;
        long long rowi;
        if (PADB) {
          int gn = col0 + n;
          rowi = (long long)((gn >> 6) + 1) * 66 + (gn & 63) + 1 + boff;
        } else {
          rowi = col0 + n;
        }
        size_t goff = (size_t)rowi * args.ldB + (k0 + chunk * 8);
        gload_lds16(Bbh + goff, bflat_h + (size_t)((r * 4 + wave) * 64) * 8);
        if (MODE <= 1)
          gload_lds16(Bbl + goff, bflat_l + (size_t)((r * 4 + wave) * 64) * 8);
      }
      __syncthreads();
      short8 afh[FM], afl[FM], bfh[FN], bfl[FN];
#pragma unroll
      for (int i = 0; i < FM; ++i) {
        afh[i] = *(const short8*)&lAh[lhi][wr * (BM / 2) + i * 16 + llo][0];
        if (MODE == 0)
          afl[i] = *(const short8*)&lAl[lhi][wr * (BM / 2) + i * 16 + llo][0];
      }
#pragma unroll
      for (int j = 0; j < FN; ++j) {
        bfh[j] = *(const short8*)&lBh[lhi][wc * (BN / 2) + j * 16 + llo][0];
        if (MODE <= 1)
          bfl[j] = *(const short8*)&lBl[lhi][wc * (BN / 2) + j * 16 + llo][0];
      }
#pragma unroll
      for (int i = 0; i < FM; ++i)
#pragma unroll
        for (int j = 0; j < FN; ++j) {
          f32x4 t = acc[i][j];
          if (MODE <= 1)
            t = __builtin_amdgcn_mfma_f32_16x16x32_bf16(afh[i], bfl[j], t, 0, 0, 0);
          if (MODE == 0)
            t = __builtin_amdgcn_mfma_f32_16x16x32_bf16(afl[i], bfh[j], t, 0, 0, 0);
          t = __builtin_amdgcn_mfma_f32_16x16x32_bf16(afh[i], bfh[j], t, 0, 0, 0);
          acc[i][j] = t;
        }
    }
  }

  float* outp = args.outf + (size_t)split * args.sSplit + (size_t)b * args.sOut;
#pragma unroll
  for (int i = 0; i < FM; ++i) {
    int mb = row0 + wr * (BM / 2) + i * 16 + lhi * 4;
#pragma unroll
    for (int j = 0; j < FN; ++j) {
      int n = col0 + wc * (BN / 2) + j * 16 + llo;
      f32x4 vv = acc[i][j] * args.alpha;
      *(f32x4*)(outp + (size_t)n * args.ldT + mb) = vv;
    }
  }
  if (SYMM) {
    if (nt != mt) {
#pragma unroll
      for (int i = 0; i < FM; ++i) {
        int mb = row0 + wr * (BM / 2) + i * 16 + lhi * 4;
#pragma unroll
        for (int j = 0; j < FN; ++j) {
          int n = col0 + wc * (BN / 2) + j * 16 + llo;
#pragma unroll
          for (int r2 = 0; r2 < 4; ++r2)
            outp[(size_t)(mb + r2) * args.ldT + n] = acc[i][j][r2] * args.alpha;
        }
      }
    }
  }
}

// Sum ns split-partials; apply (optional scale)*v+bias, relu; split-store bf16 hi/lo.
template<int LDT, bool PER_COL>
__global__ __launch_bounds__(256) void reduce_split(
    const float* __restrict__ part, long long sSplit, int ns,
    const float* __restrict__ scale, const float* __restrict__ bias,
    u16_t* __restrict__ oh, u16_t* __restrict__ ol, long long total) {
  long long i = ((long long)blockIdx.x * 256 + threadIdx.x) * 4;
  if (i >= total) return;
  f32x4 s = *(const f32x4*)(part + i);
  for (int p = 1; p < ns; ++p) s += *(const f32x4*)(part + (size_t)p * sSplit + i);
  f32x4 v;
  if (PER_COL) {
    int c = (int)(i & (LDT - 1));
    f32x4 bi = *(const f32x4*)(bias + c);
    if (scale) { f32x4 sc = *(const f32x4*)(scale + c); v = s * sc + bi; }
    else v = s + bi;
  } else {
    int r = (int)((i / LDT) & 255);
    float bi = bias[r];
    v = s + bi;
  }
  us4 h, l;
#pragma unroll
  for (int c2 = 0; c2 < 4; ++c2) {
    float vv = v[c2] > 0.f ? v[c2] : 0.f;
    u16_t hh = f2bf(vv);
    h[c2] = hh;
    l[c2] = f2bf(vv - bf2f(hh));
  }
  *(us4*)(oh + i) = h;
  if (ol) *(us4*)(ol + i) = l;
}

__global__ __launch_bounds__(256) void reduce_split_f32(
    const float* __restrict__ part, long long sSplit, int ns,
    float* __restrict__ out, long long total) {
  long long i = ((long long)blockIdx.x * 256 + threadIdx.x) * 4;
  if (i >= total) return;
  f32x4 s = *(const f32x4*)(part + i);
  for (int p = 1; p < ns; ++p) s += *(const f32x4*)(part + (size_t)p * sSplit + i);
  *(f32x4*)(out + i) = s;
}

// Row softmax over 4096, in-place fp32 + bf16 copy for PV.
__global__ __launch_bounds__(256) void softmax_k(float* S, u16_t* P) {
  const int row = blockIdx.x;
  float* Sr = S + (size_t)row * 4096;
  u16_t* Pr = P + (size_t)row * 4096;
  const int t = threadIdx.x;
  const int wave = t >> 6;
  f32x4 v[4];
  float vmax = -3.4e38f;
#pragma unroll
  for (int i = 0; i < 4; ++i) {
    v[i] = ((const f32x4*)Sr)[t + i * 256];
#pragma unroll
    for (int c = 0; c < 4; ++c) vmax = fmaxf(vmax, v[i][c]);
  }
#pragma unroll
  for (int off = 32; off; off >>= 1) vmax = fmaxf(vmax, __shfl_xor(vmax, off));
  __shared__ float red[4];
  if ((t & 63) == 0) red[wave] = vmax;
  __syncthreads();
  vmax = fmaxf(fmaxf(red[0], red[1]), fmaxf(red[2], red[3]));
  float sum = 0.f;
#pragma unroll
  for (int i = 0; i < 4; ++i)
#pragma unroll
    for (int c = 0; c < 4; ++c) { v[i][c] = __expf(v[i][c] - vmax); sum += v[i][c]; }
#pragma unroll
  for (int off = 32; off; off >>= 1) sum += __shfl_xor(sum, off);
  __shared__ float red2[4];
  if ((t & 63) == 0) red2[wave] = sum;
  __syncthreads();
  sum = red2[0] + red2[1] + red2[2] + red2[3];
  float rs = 1.0f / sum;
#pragma unroll
  for (int i = 0; i < 4; ++i) {
    f32x4 o = v[i] * rs;
    ((f32x4*)Sr)[t + i * 256] = o;
    us4 pb;
#pragma unroll
    for (int c = 0; c < 4; ++c) pb[c] = f2bf(o[c]);
    ((us4*)Pr)[t + i * 256] = pb;
  }
}

// x [2][512][4096] -> padded transposed split xT [2][4356][512] (hi/lo bf16).
__global__ __launch_bounds__(256) void xprep(const float* __restrict__ x,
                                             u16_t* __restrict__ xh, u16_t* __restrict__ xl) {
  __shared__ float tile[64][65];
  const int b = blockIdx.z, c0 = blockIdx.y * 64, n0 = blockIdx.x * 64;
  const float* xb = x + ((size_t)b * 512 + c0) * 4096 + n0;
  const int t = threadIdx.x;
  const int tr = t >> 6, tc = t & 63;
#pragma unroll
  for (int rr = 0; rr < 16; ++rr) {
    int ci = tr + rr * 4;
    tile[ci][tc] = xb[(size_t)ci * 4096 + tc];
  }
  __syncthreads();
#pragma unroll
  for (int rr = 0; rr < 16; ++rr) {
    int nj = rr * 4 + tr;
    float v = tile[tc][nj];
    size_t rp = (size_t)(blockIdx.x + 1) * 66 + nj + 1;
    size_t o = ((size_t)b * 4356 + rp) * 512 + c0 + tc;
    u16_t hh = f2bf(v);
    xh[o] = hh;
    xl[o] = f2bf(v - bf2f(hh));
  }
}

// wv1 [256][512][3][3] -> [9][256][512] hi/lo
__global__ __launch_bounds__(256) void wprep(const float* __restrict__ wv1,
                                             u16_t* __restrict__ wh, u16_t* __restrict__ wl) {
  size_t i = (size_t)blockIdx.x * 256 + threadIdx.x;
  const size_t total = 9ull * 256 * 512;
  if (i >= total) return;
  int tp = (int)(i / (256 * 512));
  int rem = (int)(i % (256 * 512));
  int o = rem / 512, c = rem % 512;
  float v = wv1[((size_t)o * 512 + c) * 9 + tp];
  u16_t hh = f2bf(v);
  wh[i] = hh;
  wl[i] = f2bf(v - bf2f(hh));
}

__global__ __launch_bounds__(256) void splitk(const float* __restrict__ s,
                                              u16_t* __restrict__ h, u16_t* __restrict__ l, int n) {
  int i = blockIdx.x * 256 + threadIdx.x;
  if (i < n) {
    float v = s[i];
    u16_t hh = f2bf(v);
    h[i] = hh;
    l[i] = f2bf(v - bf2f(hh));
  }
}

__global__ __launch_bounds__(256) void bnprep(const float* g, const float* be, const float* mu,
                                              const float* var, const float* bk,
                                              float* sA, float* sB) {
  int i = threadIdx.x;
  float s = g[i] * rsqrtf(var[i] + 1e-5f);
  sA[i] = s;
  sB[i] = (bk[i] - mu[i]) * s + be[i];
}

extern "C" void kernel_launch(void* const* d_in, const int* in_sizes, int n_in,
                              void* d_out, int out_size, void* d_ws, size_t ws_size,
                              hipStream_t stream) {
  (void)in_sizes; (void)n_in; (void)out_size; (void)ws_size;
  const float* x   = (const float*)d_in[0];
  const float* wk  = (const float*)d_in[1];
  const float* bk  = (const float*)d_in[2];
  const float* gam = (const float*)d_in[3];
  const float* bet = (const float*)d_in[4];
  const float* mu  = (const float*)d_in[5];
  const float* var = (const float*)d_in[6];
  const float* wv1 = (const float*)d_in[7];
  const float* bv1 = (const float*)d_in[8];
  const float* wv2 = (const float*)d_in[9];
  const float* bv2 = (const float*)d_in[10];

  const int B = 2;
  const size_t XT_E  = (size_t)B * 4356 * 512;
  const size_t WK_E  = 256 * 512;
  const size_t WV1_E = 9ull * 256 * 512;
  const size_t WV2_E = 256 * 256;
  const size_t FT_E  = (size_t)B * 4096 * 256;   // 2,097,152
  const size_t P_E   = (size_t)B * 4096 * 4096;

  size_t off = 0;
  auto carve = [&](size_t bytes) -> char* {
    off = (off + 255) & ~(size_t)255;
    char* p = (char*)d_ws + off;
    off += bytes;
    return p;
  };
  u16_t* xh  = (u16_t*)carve(XT_E * 2);
  u16_t* xl  = (u16_t*)carve(XT_E * 2);
  u16_t* wkh = (u16_t*)carve(WK_E * 2);
  u16_t* wkl = (u16_t*)carve(WK_E * 2);
  u16_t* w1h = (u16_t*)carve(WV1_E * 2);
  u16_t* w1l = (u16_t*)carve(WV1_E * 2);
  u16_t* w2h = (u16_t*)carve(WV2_E * 2);
  u16_t* w2l = (u16_t*)carve(WV2_E * 2);
  u16_t* fth = (u16_t*)carve(FT_E * 2);
  u16_t* ftl = (u16_t*)carve(FT_E * 2);
  u16_t* v1h = (u16_t*)carve(FT_E * 2);
  u16_t* v1l = (u16_t*)carve(FT_E * 2);
  u16_t* vh  = (u16_t*)carve(FT_E * 2);
  u16_t* vl  = (u16_t*)carve(FT_E * 2);
  u16_t* Pb  = (u16_t*)carve(P_E * 2);
  float* bnA = (float*)carve(256 * 4);
  float* bnB = (float*)carve(256 * 4);

  // Aliased scratch (lifetimes verified):
  //  big_part (Pb region): feat/conv/wv2 partials; all complete before softmax
  //            writes Pb. max 9*8.39MB = 75.5MB < 134MB.
  //  pv_part (ws start): PV partials 4*8.39MB = 33.5MB; xh/xl + weights dead
  //            by PV time. vh/vl live at ~40.1MB offset, beyond partials.
  float* big_part = (float*)Pb;
  float* pv_part  = (float*)d_ws;

  float* ctx = (float*)d_out;                          // [2][256][4096]
  float* sim = (float*)d_out + (size_t)B * 256 * 4096; // [2][4096][4096]

  const long long FT_LL = (long long)FT_E;

  hipMemsetAsync(xh, 0, XT_E * 2, stream);
  hipMemsetAsync(xl, 0, XT_E * 2, stream);
  bnprep<<<1, 256, 0, stream>>>(gam, bet, mu, var, bk, bnA, bnB);
  splitk<<<(int)((WK_E + 255) / 256), 256, 0, stream>>>(wk, wkh, wkl, (int)WK_E);
  splitk<<<(int)((WV2_E + 255) / 256), 256, 0, stream>>>(wv2, w2h, w2l, (int)WV2_E);
  wprep<<<(int)((WV1_E + 255) / 256), 256, 0, stream>>>(wv1, w1h, w1l);
  xprep<<<dim3(64, 8, 2), 256, 0, stream>>>(x, xh, xl);

  // ---- feat = relu(BN(wk @ x)): fused hi/lo MODE0, 2 K-splits of 256
  {
    GemmArgs a = {};
    a.segs[0] = {wkh,       wkl,       xh,       xl,       0};
    a.segs[1] = {wkh + 256, wkl + 256, xh + 256, xl + 256, 0};
    a.nseg = 2; a.segs_per_split = 1; a.K = 256; a.ldA = 512; a.ldB = 512;
    a.sA = 0; a.sB = (long long)4356 * 512; a.alpha = 1.f;
    a.outf = big_part; a.sOut = (long long)4096 * 256; a.sSplit = FT_LL; a.ldT = 256;
    gemm_tn<64, 128, 0, true, false><<<dim3(32, 4, 4), 256, 0, stream>>>(a);
    reduce_split<256, true><<<2048, 256, 0, stream>>>(big_part, FT_LL, 2, bnA, bnB, fth, ftl, FT_LL);
  }
  // ---- QK: S = featT @ featT^T * Ck^-0.5, MODE0, symmetric upper-triangle
  {
    GemmArgs a = {};
    a.segs[0] = {fth, ftl, fth, ftl, 0};
    a.nseg = 1; a.segs_per_split = 1; a.K = 256; a.ldA = 256; a.ldB = 256;
    a.sA = (long long)4096 * 256; a.sB = (long long)4096 * 256; a.alpha = 0.0625f;
    a.outf = sim; a.sOut = (long long)4096 * 4096; a.sSplit = 0; a.ldT = 4096;
    gemm_tn<128, 128, 0, false, true><<<dim3(528, 1, 2), 256, 0, stream>>>(a);
  }
  // ---- conv3x3 + bias + relu -> v1T: 9 tap-splits, MODE2 (single MFMA)
  {
    GemmArgs a = {};
    for (int ty = 0; ty < 3; ++ty)
      for (int tx = 0; tx < 3; ++tx) {
        int tp = ty * 3 + tx;
        int boff = (ty - 1) * 66 + (tx - 1);
        a.segs[tp] = {w1h + (size_t)tp * 131072, nullptr, xh, nullptr, boff};
      }
    a.nseg = 9; a.segs_per_split = 1; a.K = 512; a.ldA = 512; a.ldB = 512;
    a.sA = 0; a.sB = (long long)4356 * 512; a.alpha = 1.f;
    a.outf = big_part; a.sOut = (long long)4096 * 256; a.sSplit = FT_LL; a.ldT = 256;
    gemm_tn<128, 128, 2, true, false><<<dim3(32, 2, 18), 256, 0, stream>>>(a);
    reduce_split<256, true><<<2048, 256, 0, stream>>>(big_part, FT_LL, 9, nullptr, bv1, v1h, v1l, FT_LL);
  }
  // ---- v = relu(wv2 @ v1 + bv2), flipped (M=4096, N=256), MODE0, 2 K-splits
  {
    GemmArgs a = {};
    a.segs[0] = {v1h,       v1l,       w2h,       w2l,       0};
    a.segs[1] = {v1h + 128, v1l + 128, w2h + 128, w2l + 128, 0};
    a.nseg = 2; a.segs_per_split = 1; a.K = 128; a.ldA = 256; a.ldB = 256;
    a.sA = (long long)4096 * 256; a.sB = 0; a.alpha = 1.f;
    a.outf = big_part; a.sOut = (long long)256 * 4096; a.sSplit = FT_LL; a.ldT = 4096;
    gemm_tn<128, 64, 0, false, false><<<dim3(4, 32, 4), 256, 0, stream>>>(a);
    reduce_split<4096, false><<<2048, 256, 0, stream>>>(big_part, FT_LL, 2, nullptr, bv2, vh, nullptr, FT_LL);
  }
  softmax_k<<<B * 4096, 256, 0, stream>>>(sim, Pb);
  // ---- ctx = P @ v^T: MODE2 (P bf16 exact, v_h only), 4 K-splits of 1024
  {
    GemmArgs a = {};
    for (int q = 0; q < 4; ++q)
      a.segs[q] = {Pb + (size_t)q * 1024, nullptr, vh + (size_t)q * 1024, nullptr, 0};
    a.nseg = 4; a.segs_per_split = 1; a.K = 1024; a.ldA = 4096; a.ldB = 4096;
    a.sA = (long long)4096 * 4096; a.sB = (long long)256 * 4096; a.alpha = 1.f;
    a.outf = pv_part; a.sOut = (long long)256 * 4096; a.sSplit = FT_LL; a.ldT = 4096;
    gemm_tn<128, 128, 2, false, false><<<dim3(2, 32, 8), 256, 0, stream>>>(a);
    reduce_split_f32<<<2048, 256, 0, stream>>>(pv_part, FT_LL, 4, ctx, FT_LL);
  }
  (void)vl; (void)w1l;
}

// Round 5
// 312.684 us; speedup vs baseline: 2.2198x; 1.0255x over previous
//
#include <hip/hip_runtime.h>
#include <hip/hip_bf16.h>
#include <stdint.h>

typedef unsigned short u16_t;
typedef __attribute__((ext_vector_type(8))) short short8;
typedef __attribute__((ext_vector_type(4))) float f32x4;
typedef __attribute__((ext_vector_type(4))) unsigned short us4;

__device__ __forceinline__ float bf2f(u16_t u) {
  union { unsigned int i; float f; } c; c.i = ((unsigned int)u) << 16; return c.f;
}
__device__ __forceinline__ u16_t f2bf(float f) {
  union { float f; unsigned int i; } c; c.f = f;
  unsigned int x = c.i;
  unsigned int r = x + 0x7fffu + ((x >> 16) & 1u);
  return (u16_t)(r >> 16);
}

__device__ __forceinline__ void gload_lds16(const u16_t* g, u16_t* l) {
  __builtin_amdgcn_global_load_lds(
      (const __attribute__((address_space(1))) void*)g,
      (__attribute__((address_space(3))) void*)(unsigned int)(uintptr_t)l,
      16, 0, 0);
}

struct Seg {
  const u16_t* Ah;
  const u16_t* Al;
  const u16_t* Bh;
  const u16_t* Bl;
  int boff;   // padded-row offset for conv taps
};

struct GemmArgs {
  Seg segs[9];
  int nseg;
  int segs_per_split;
  int K;                 // K per seg
  int ldA, ldB;
  long long sA, sB;      // batch strides (elements)
  float alpha;
  float* outf;           // fp32 output (final or split partials)
  long long sOut;
  long long sSplit;
  int ldT;
};

// Fused-split TN GEMM.
// MODE 0: acc += Ah*Bh + Al*Bh + Ah*Bl   (emulated fp32)
// MODE 1: acc += Ah*Bh + Ah*Bl           (A exact bf16, B split)
// MODE 2: acc += Ah*Bh                   (both bf16-rounded)
// fp32 transposed store: out[split*sSplit + b*sOut + n*ldT + m] (float4 over m)
// SYMM: blockIdx.x = upper-triangle tile index (NT=32), mirror-store transposed.
template<int BM, int BN, int MODE, bool PADB, bool SYMM>
__global__ __launch_bounds__(256, 4) void gemm_tn(GemmArgs args) {
  constexpr int FM = BM / 32, FN = BN / 32;
  __shared__ __align__(16) u16_t lAh[4][BM][8];
  __shared__ __align__(16) u16_t lAl[(MODE == 0) ? 4 : 1][BM][8];
  __shared__ __align__(16) u16_t lBh[4][BN][8];
  __shared__ __align__(16) u16_t lBl[(MODE <= 1) ? 4 : 1][BN][8];
  const int tid = threadIdx.x;
  const int wave = tid >> 6, lane = tid & 63;
  const int lhi = lane >> 4, llo = lane & 15;
  const int wr = wave >> 1, wc = wave & 1;
  int nt, mt, b, split;
  if (SYMM) {
    b = blockIdx.z; split = 0;
    int t = blockIdx.x, r = 0;
    while (t >= 32 - r) { t -= 32 - r; ++r; }
    mt = r; nt = r + t;
  } else {
    nt = blockIdx.x; mt = blockIdx.y;
    b = blockIdx.z & 1; split = blockIdx.z >> 1;
  }
  const int row0 = mt * BM, col0 = nt * BN;

  f32x4 acc[FM][FN];
  const f32x4 zero4 = {0.f, 0.f, 0.f, 0.f};
#pragma unroll
  for (int i = 0; i < FM; ++i)
#pragma unroll
    for (int j = 0; j < FN; ++j) acc[i][j] = zero4;

  constexpr int RA = BM / 64;
  constexpr int RB = BN / 64;
  u16_t* aflat_h = &lAh[0][0][0];
  u16_t* aflat_l = &lAl[0][0][0];
  u16_t* bflat_h = &lBh[0][0][0];
  u16_t* bflat_l = &lBl[0][0][0];

  const int s0 = split * args.segs_per_split;
  int s1 = s0 + args.segs_per_split;
  if (s1 > args.nseg) s1 = args.nseg;

  for (int s = s0; s < s1; ++s) {
    const u16_t* Abh = args.segs[s].Ah + (size_t)b * args.sA;
    const u16_t* Abl = args.segs[s].Al + (size_t)b * args.sA;
    const u16_t* Bbh = args.segs[s].Bh + (size_t)b * args.sB;
    const u16_t* Bbl = args.segs[s].Bl + (size_t)b * args.sB;
    const int boff = args.segs[s].boff;
    for (int k0 = 0; k0 < args.K; k0 += 32) {
      __syncthreads();
#pragma unroll
      for (int r = 0; r < RA; ++r) {
        int idx = (r * 4 + wave) * 64 + lane;
        int chunk = idx / BM, m = idx % BM;
        size_t goff = (size_t)(row0 + m) * args.ldA + (k0 + chunk * 8);
        gload_lds16(Abh + goff, aflat_h + (size_t)((r * 4 + wave) * 64) * 8);
        if (MODE == 0)
          gload_lds16(Abl + goff, aflat_l + (size_t)((r * 4 + wave) * 64) * 8);
      }
#pragma unroll
      for (int r = 0; r < RB; ++r) {
        int idx = (r * 4 + wave) * 64 + lane;
        int chunk = idx / BN, n = idx % BN;
        long long rowi;
        if (PADB) {
          int gn = col0 + n;
          rowi = (long long)((gn >> 6) + 1) * 66 + (gn & 63) + 1 + boff;
        } else {
          rowi = col0 + n;
        }
        size_t goff = (size_t)rowi * args.ldB + (k0 + chunk * 8);
        gload_lds16(Bbh + goff, bflat_h + (size_t)((r * 4 + wave) * 64) * 8);
        if (MODE <= 1)
          gload_lds16(Bbl + goff, bflat_l + (size_t)((r * 4 + wave) * 64) * 8);
      }
      __syncthreads();
      short8 afh[FM], afl[FM], bfh[FN], bfl[FN];
#pragma unroll
      for (int i = 0; i < FM; ++i) {
        afh[i] = *(const short8*)&lAh[lhi][wr * (BM / 2) + i * 16 + llo][0];
        if (MODE == 0)
          afl[i] = *(const short8*)&lAl[lhi][wr * (BM / 2) + i * 16 + llo][0];
      }
#pragma unroll
      for (int j = 0; j < FN; ++j) {
        bfh[j] = *(const short8*)&lBh[lhi][wc * (BN / 2) + j * 16 + llo][0];
        if (MODE <= 1)
          bfl[j] = *(const short8*)&lBl[lhi][wc * (BN / 2) + j * 16 + llo][0];
      }
#pragma unroll
      for (int i = 0; i < FM; ++i)
#pragma unroll
        for (int j = 0; j < FN; ++j) {
          f32x4 t = acc[i][j];
          if (MODE <= 1)
            t = __builtin_amdgcn_mfma_f32_16x16x32_bf16(afh[i], bfl[j], t, 0, 0, 0);
          if (MODE == 0)
            t = __builtin_amdgcn_mfma_f32_16x16x32_bf16(afl[i], bfh[j], t, 0, 0, 0);
          t = __builtin_amdgcn_mfma_f32_16x16x32_bf16(afh[i], bfh[j], t, 0, 0, 0);
          acc[i][j] = t;
        }
    }
  }

  float* outp = args.outf + (size_t)split * args.sSplit + (size_t)b * args.sOut;
#pragma unroll
  for (int i = 0; i < FM; ++i) {
    int mb = row0 + wr * (BM / 2) + i * 16 + lhi * 4;
#pragma unroll
    for (int j = 0; j < FN; ++j) {
      int n = col0 + wc * (BN / 2) + j * 16 + llo;
      f32x4 vv = acc[i][j] * args.alpha;
      *(f32x4*)(outp + (size_t)n * args.ldT + mb) = vv;
    }
  }
  if (SYMM) {
    if (nt != mt) {
#pragma unroll
      for (int i = 0; i < FM; ++i) {
        int mb = row0 + wr * (BM / 2) + i * 16 + lhi * 4;
#pragma unroll
        for (int j = 0; j < FN; ++j) {
          int n = col0 + wc * (BN / 2) + j * 16 + llo;
#pragma unroll
          for (int r2 = 0; r2 < 4; ++r2)
            outp[(size_t)(mb + r2) * args.ldT + n] = acc[i][j][r2] * args.alpha;
        }
      }
    }
  }
}

// Zero ONLY the 260 pad rows per batch of the padded xT layout (hi+lo bufs).
// Row space: 4356 = 66*66. Pad rows: rp<66, rp>=4290, rp%66==0, rp%66==65.
__global__ __launch_bounds__(256) void zeropad(u16_t* __restrict__ xh, u16_t* __restrict__ xl) {
  int rowi = blockIdx.x % 260;
  int b = blockIdx.x / 260;
  int rp;
  if (rowi < 66) rp = rowi;
  else if (rowi < 132) rp = 4290 + (rowi - 66);
  else { int g = (rowi - 132) >> 1; rp = (g + 1) * 66 + ((rowi - 132) & 1) * 65; }
  size_t base = ((size_t)b * 4356 + rp) * 512;
  int t = threadIdx.x;
  const us4 z = {0, 0, 0, 0};
  if (t < 128) *(us4*)(xh + base + (size_t)t * 4) = z;
  else *(us4*)(xl + base + (size_t)(t - 128) * 4) = z;
}

// Sum ns split-partials; apply (optional scale)*v+bias, relu; split-store bf16 hi/lo.
template<int LDT, bool PER_COL>
__global__ __launch_bounds__(256) void reduce_split(
    const float* __restrict__ part, long long sSplit, int ns,
    const float* __restrict__ scale, const float* __restrict__ bias,
    u16_t* __restrict__ oh, u16_t* __restrict__ ol, long long total) {
  long long i = ((long long)blockIdx.x * 256 + threadIdx.x) * 4;
  if (i >= total) return;
  f32x4 s = *(const f32x4*)(part + i);
  for (int p = 1; p < ns; ++p) s += *(const f32x4*)(part + (size_t)p * sSplit + i);
  f32x4 v;
  if (PER_COL) {
    int c = (int)(i & (LDT - 1));
    f32x4 bi = *(const f32x4*)(bias + c);
    if (scale) { f32x4 sc = *(const f32x4*)(scale + c); v = s * sc + bi; }
    else v = s + bi;
  } else {
    int r = (int)((i / LDT) & 255);
    float bi = bias[r];
    v = s + bi;
  }
  us4 h, l;
#pragma unroll
  for (int c2 = 0; c2 < 4; ++c2) {
    float vv = v[c2] > 0.f ? v[c2] : 0.f;
    u16_t hh = f2bf(vv);
    h[c2] = hh;
    l[c2] = f2bf(vv - bf2f(hh));
  }
  *(us4*)(oh + i) = h;
  if (ol) *(us4*)(ol + i) = l;
}

__global__ __launch_bounds__(256) void reduce_split_f32(
    const float* __restrict__ part, long long sSplit, int ns,
    float* __restrict__ out, long long total) {
  long long i = ((long long)blockIdx.x * 256 + threadIdx.x) * 4;
  if (i >= total) return;
  f32x4 s = *(const f32x4*)(part + i);
  for (int p = 1; p < ns; ++p) s += *(const f32x4*)(part + (size_t)p * sSplit + i);
  *(f32x4*)(out + i) = s;
}

// Row softmax over 4096, in-place fp32 + bf16 copy for PV.
__global__ __launch_bounds__(256) void softmax_k(float* S, u16_t* P) {
  const int row = blockIdx.x;
  float* Sr = S + (size_t)row * 4096;
  u16_t* Pr = P + (size_t)row * 4096;
  const int t = threadIdx.x;
  const int wave = t >> 6;
  f32x4 v[4];
  float vmax = -3.4e38f;
#pragma unroll
  for (int i = 0; i < 4; ++i) {
    v[i] = ((const f32x4*)Sr)[t + i * 256];
#pragma unroll
    for (int c = 0; c < 4; ++c) vmax = fmaxf(vmax, v[i][c]);
  }
#pragma unroll
  for (int off = 32; off; off >>= 1) vmax = fmaxf(vmax, __shfl_xor(vmax, off));
  __shared__ float red[4];
  if ((t & 63) == 0) red[wave] = vmax;
  __syncthreads();
  vmax = fmaxf(fmaxf(red[0], red[1]), fmaxf(red[2], red[3]));
  float sum = 0.f;
#pragma unroll
  for (int i = 0; i < 4; ++i)
#pragma unroll
    for (int c = 0; c < 4; ++c) { v[i][c] = __expf(v[i][c] - vmax); sum += v[i][c]; }
#pragma unroll
  for (int off = 32; off; off >>= 1) sum += __shfl_xor(sum, off);
  __shared__ float red2[4];
  if ((t & 63) == 0) red2[wave] = sum;
  __syncthreads();
  sum = red2[0] + red2[1] + red2[2] + red2[3];
  float rs = 1.0f / sum;
#pragma unroll
  for (int i = 0; i < 4; ++i) {
    f32x4 o = v[i] * rs;
    ((f32x4*)Sr)[t + i * 256] = o;
    us4 pb;
#pragma unroll
    for (int c = 0; c < 4; ++c) pb[c] = f2bf(o[c]);
    ((us4*)Pr)[t + i * 256] = pb;
  }
}

// x [2][512][4096] -> padded transposed split xT [2][4356][512] (hi/lo bf16).
__global__ __launch_bounds__(256) void xprep(const float* __restrict__ x,
                                             u16_t* __restrict__ xh, u16_t* __restrict__ xl) {
  __shared__ float tile[64][65];
  const int b = blockIdx.z, c0 = blockIdx.y * 64, n0 = blockIdx.x * 64;
  const float* xb = x + ((size_t)b * 512 + c0) * 4096 + n0;
  const int t = threadIdx.x;
  const int tr = t >> 6, tc = t & 63;
#pragma unroll
  for (int rr = 0; rr < 16; ++rr) {
    int ci = tr + rr * 4;
    tile[ci][tc] = xb[(size_t)ci * 4096 + tc];
  }
  __syncthreads();
#pragma unroll
  for (int rr = 0; rr < 16; ++rr) {
    int nj = rr * 4 + tr;
    float v = tile[tc][nj];
    size_t rp = (size_t)(blockIdx.x + 1) * 66 + nj + 1;
    size_t o = ((size_t)b * 4356 + rp) * 512 + c0 + tc;
    u16_t hh = f2bf(v);
    xh[o] = hh;
    xl[o] = f2bf(v - bf2f(hh));
  }
}

// wv1 [256][512][3][3] -> [9][256][512] hi/lo
__global__ __launch_bounds__(256) void wprep(const float* __restrict__ wv1,
                                             u16_t* __restrict__ wh, u16_t* __restrict__ wl) {
  size_t i = (size_t)blockIdx.x * 256 + threadIdx.x;
  const size_t total = 9ull * 256 * 512;
  if (i >= total) return;
  int tp = (int)(i / (256 * 512));
  int rem = (int)(i % (256 * 512));
  int o = rem / 512, c = rem % 512;
  float v = wv1[((size_t)o * 512 + c) * 9 + tp];
  u16_t hh = f2bf(v);
  wh[i] = hh;
  wl[i] = f2bf(v - bf2f(hh));
}

__global__ __launch_bounds__(256) void splitk(const float* __restrict__ s,
                                              u16_t* __restrict__ h, u16_t* __restrict__ l, int n) {
  int i = blockIdx.x * 256 + threadIdx.x;
  if (i < n) {
    float v = s[i];
    u16_t hh = f2bf(v);
    h[i] = hh;
    l[i] = f2bf(v - bf2f(hh));
  }
}

__global__ __launch_bounds__(256) void bnprep(const float* g, const float* be, const float* mu,
                                              const float* var, const float* bk,
                                              float* sA, float* sB) {
  int i = threadIdx.x;
  float s = g[i] * rsqrtf(var[i] + 1e-5f);
  sA[i] = s;
  sB[i] = (bk[i] - mu[i]) * s + be[i];
}

extern "C" void kernel_launch(void* const* d_in, const int* in_sizes, int n_in,
                              void* d_out, int out_size, void* d_ws, size_t ws_size,
                              hipStream_t stream) {
  (void)in_sizes; (void)n_in; (void)out_size; (void)ws_size;
  const float* x   = (const float*)d_in[0];
  const float* wk  = (const float*)d_in[1];
  const float* bk  = (const float*)d_in[2];
  const float* gam = (const float*)d_in[3];
  const float* bet = (const float*)d_in[4];
  const float* mu  = (const float*)d_in[5];
  const float* var = (const float*)d_in[6];
  const float* wv1 = (const float*)d_in[7];
  const float* bv1 = (const float*)d_in[8];
  const float* wv2 = (const float*)d_in[9];
  const float* bv2 = (const float*)d_in[10];

  const int B = 2;
  const size_t XT_E  = (size_t)B * 4356 * 512;
  const size_t WK_E  = 256 * 512;
  const size_t WV1_E = 9ull * 256 * 512;
  const size_t WV2_E = 256 * 256;
  const size_t FT_E  = (size_t)B * 4096 * 256;   // 2,097,152
  const size_t P_E   = (size_t)B * 4096 * 4096;

  size_t off = 0;
  auto carve = [&](size_t bytes) -> char* {
    off = (off + 255) & ~(size_t)255;
    char* p = (char*)d_ws + off;
    off += bytes;
    return p;
  };
  u16_t* xh  = (u16_t*)carve(XT_E * 2);
  u16_t* xl  = (u16_t*)carve(XT_E * 2);
  u16_t* wkh = (u16_t*)carve(WK_E * 2);
  u16_t* wkl = (u16_t*)carve(WK_E * 2);
  u16_t* w1h = (u16_t*)carve(WV1_E * 2);
  u16_t* w1l = (u16_t*)carve(WV1_E * 2);
  u16_t* w2h = (u16_t*)carve(WV2_E * 2);
  u16_t* w2l = (u16_t*)carve(WV2_E * 2);
  u16_t* fth = (u16_t*)carve(FT_E * 2);
  u16_t* ftl = (u16_t*)carve(FT_E * 2);
  u16_t* v1h = (u16_t*)carve(FT_E * 2);
  u16_t* v1l = (u16_t*)carve(FT_E * 2);
  u16_t* vh  = (u16_t*)carve(FT_E * 2);
  u16_t* vl  = (u16_t*)carve(FT_E * 2);
  u16_t* Pb  = (u16_t*)carve(P_E * 2);
  float* bnA = (float*)carve(256 * 4);
  float* bnB = (float*)carve(256 * 4);

  // Aliased scratch (lifetimes verified):
  //  big_part (Pb region): feat/conv/wv2 partials; all complete before softmax
  //            writes Pb. conv uses 9*8.39MB = 75.5MB (overruns Pb's 67MB into
  //            bnA/bnB + slack — bnA/bnB are dead by conv time; recomputed per call).
  //  pv_part (ws start): PV partials 4*8.39MB = 33.5MB; xh/xl + weights + fth/ftl
  //            dead by PV time; all rewritten per call before reuse.
  float* big_part = (float*)Pb;
  float* pv_part  = (float*)d_ws;

  float* ctx = (float*)d_out;                          // [2][256][4096]
  float* sim = (float*)d_out + (size_t)B * 256 * 4096; // [2][4096][4096]

  const long long FT_LL = (long long)FT_E;

  zeropad<<<520, 256, 0, stream>>>(xh, xl);
  bnprep<<<1, 256, 0, stream>>>(gam, bet, mu, var, bk, bnA, bnB);
  splitk<<<(int)((WK_E + 255) / 256), 256, 0, stream>>>(wk, wkh, wkl, (int)WK_E);
  splitk<<<(int)((WV2_E + 255) / 256), 256, 0, stream>>>(wv2, w2h, w2l, (int)WV2_E);
  wprep<<<(int)((WV1_E + 255) / 256), 256, 0, stream>>>(wv1, w1h, w1l);
  xprep<<<dim3(64, 8, 2), 256, 0, stream>>>(x, xh, xl);

  // ---- feat = relu(BN(wk @ x)): fused hi/lo MODE0, 2 K-splits of 256
  {
    GemmArgs a = {};
    a.segs[0] = {wkh,       wkl,       xh,       xl,       0};
    a.segs[1] = {wkh + 256, wkl + 256, xh + 256, xl + 256, 0};
    a.nseg = 2; a.segs_per_split = 1; a.K = 256; a.ldA = 512; a.ldB = 512;
    a.sA = 0; a.sB = (long long)4356 * 512; a.alpha = 1.f;
    a.outf = big_part; a.sOut = (long long)4096 * 256; a.sSplit = FT_LL; a.ldT = 256;
    gemm_tn<64, 128, 0, true, false><<<dim3(32, 4, 4), 256, 0, stream>>>(a);
    reduce_split<256, true><<<2048, 256, 0, stream>>>(big_part, FT_LL, 2, bnA, bnB, fth, ftl, FT_LL);
  }
  // ---- QK: S = featT @ featT^T * Ck^-0.5, MODE0, symmetric upper-triangle
  {
    GemmArgs a = {};
    a.segs[0] = {fth, ftl, fth, ftl, 0};
    a.nseg = 1; a.segs_per_split = 1; a.K = 256; a.ldA = 256; a.ldB = 256;
    a.sA = (long long)4096 * 256; a.sB = (long long)4096 * 256; a.alpha = 0.0625f;
    a.outf = sim; a.sOut = (long long)4096 * 4096; a.sSplit = 0; a.ldT = 4096;
    gemm_tn<128, 128, 0, false, true><<<dim3(528, 1, 2), 256, 0, stream>>>(a);
  }
  // ---- conv3x3 + bias + relu -> v1T: 9 tap-splits, MODE2 (single MFMA)
  {
    GemmArgs a = {};
    for (int ty = 0; ty < 3; ++ty)
      for (int tx = 0; tx < 3; ++tx) {
        int tp = ty * 3 + tx;
        int boff = (ty - 1) * 66 + (tx - 1);
        a.segs[tp] = {w1h + (size_t)tp * 131072, nullptr, xh, nullptr, boff};
      }
    a.nseg = 9; a.segs_per_split = 1; a.K = 512; a.ldA = 512; a.ldB = 512;
    a.sA = 0; a.sB = (long long)4356 * 512; a.alpha = 1.f;
    a.outf = big_part; a.sOut = (long long)4096 * 256; a.sSplit = FT_LL; a.ldT = 256;
    gemm_tn<128, 128, 2, true, false><<<dim3(32, 2, 18), 256, 0, stream>>>(a);
    reduce_split<256, true><<<2048, 256, 0, stream>>>(big_part, FT_LL, 9, nullptr, bv1, v1h, v1l, FT_LL);
  }
  // ---- v = relu(wv2 @ v1 + bv2), flipped (M=4096, N=256), MODE0, 2 K-splits
  {
    GemmArgs a = {};
    a.segs[0] = {v1h,       v1l,       w2h,       w2l,       0};
    a.segs[1] = {v1h + 128, v1l + 128, w2h + 128, w2l + 128, 0};
    a.nseg = 2; a.segs_per_split = 1; a.K = 128; a.ldA = 256; a.ldB = 256;
    a.sA = (long long)4096 * 256; a.sB = 0; a.alpha = 1.f;
    a.outf = big_part; a.sOut = (long long)256 * 4096; a.sSplit = FT_LL; a.ldT = 4096;
    gemm_tn<128, 64, 0, false, false><<<dim3(4, 32, 4), 256, 0, stream>>>(a);
    reduce_split<4096, false><<<2048, 256, 0, stream>>>(big_part, FT_LL, 2, nullptr, bv2, vh, nullptr, FT_LL);
  }
  softmax_k<<<B * 4096, 256, 0, stream>>>(sim, Pb);
  // ---- ctx = P @ v^T: MODE2 (P bf16 exact, v_h only), 4 K-splits of 1024
  {
    GemmArgs a = {};
    for (int q = 0; q < 4; ++q)
      a.segs[q] = {Pb + (size_t)q * 1024, nullptr, vh + (size_t)q * 1024, nullptr, 0};
    a.nseg = 4; a.segs_per_split = 1; a.K = 1024; a.ldA = 4096; a.ldB = 4096;
    a.sA = (long long)4096 * 4096; a.sB = (long long)256 * 4096; a.alpha = 1.f;
    a.outf = pv_part; a.sOut = (long long)256 * 4096; a.sSplit = FT_LL; a.ldT = 4096;
    gemm_tn<128, 128, 2, false, false><<<dim3(2, 32, 8), 256, 0, stream>>>(a);
    reduce_split_f32<<<2048, 256, 0, stream>>>(pv_part, FT_LL, 4, ctx, FT_LL);
  }
  (void)vl; (void)w1l;
}

// Round 6
// 281.133 us; speedup vs baseline: 2.4689x; 1.1122x over previous
//
#include <hip/hip_runtime.h>
#include <hip/hip_bf16.h>
#include <stdint.h>

typedef unsigned short u16_t;
typedef __attribute__((ext_vector_type(8))) short short8;
typedef __attribute__((ext_vector_type(4))) float f32x4;
typedef __attribute__((ext_vector_type(4))) unsigned short us4;

__device__ __forceinline__ float bf2f(u16_t u) {
  union { unsigned int i; float f; } c; c.i = ((unsigned int)u) << 16; return c.f;
}
__device__ __forceinline__ u16_t f2bf(float f) {
  union { float f; unsigned int i; } c; c.f = f;
  unsigned int x = c.i;
  unsigned int r = x + 0x7fffu + ((x >> 16) & 1u);
  return (u16_t)(r >> 16);
}

__device__ __forceinline__ void gload_lds16(const u16_t* g, u16_t* l) {
  __builtin_amdgcn_global_load_lds(
      (const __attribute__((address_space(1))) void*)g,
      (__attribute__((address_space(3))) void*)(unsigned int)(uintptr_t)l,
      16, 0, 0);
}

struct Seg {
  const u16_t* Ah;
  const u16_t* Al;
  const u16_t* Bh;
  const u16_t* Bl;
  int boff;   // padded-row offset for conv taps
};

struct GemmArgs {
  Seg segs[9];
  int nseg;
  int segs_per_split;
  int K;                 // K per seg
  int ldA, ldB;
  long long sA, sB;      // batch strides (elements)
  float alpha;
  float* outf;           // fp32 output (final or split partials)
  long long sOut;
  long long sSplit;
  int ldT;
};

// Fused-split TN GEMM.
// MODE 0: acc += Ah*Bh + Al*Bh + Ah*Bl   (emulated fp32)
// MODE 1: acc += Ah*Bh + Ah*Bl           (A hi only, B split)
// MODE 2: acc += Ah*Bh                   (both bf16-rounded)
// fp32 transposed store: out[split*sSplit + b*sOut + n*ldT + m] (float4 over m)
// SYMM: blockIdx.x = upper-triangle tile index (NT=32); mirror block stored
//       coalesced via LDS transpose (aliases staging smem after K-loop).
template<int BM, int BN, int MODE, bool PADB, bool SYMM>
__global__ __launch_bounds__(256, 4) void gemm_tn(GemmArgs args) {
  constexpr int FM = BM / 32, FN = BN / 32;
  constexpr int AH_E = 4 * BM * 8;
  constexpr int AL_E = (MODE == 0) ? 4 * BM * 8 : 8;
  constexpr int BH_E = 4 * BN * 8;
  constexpr int BL_E = (MODE <= 1) ? 4 * BN * 8 : 8;
  constexpr int SM_E = AH_E + AL_E + BH_E + BL_E;
  static_assert(!SYMM || (size_t)SM_E * 2 >= 32 * 132 * 4, "tbuf alias too small");
  __shared__ __align__(16) u16_t smem[SM_E];
  u16_t* aflat_h = smem;
  u16_t* aflat_l = smem + AH_E;
  u16_t* bflat_h = smem + AH_E + AL_E;
  u16_t* bflat_l = smem + AH_E + AL_E + BH_E;

  const int tid = threadIdx.x;
  const int wave = tid >> 6, lane = tid & 63;
  const int lhi = lane >> 4, llo = lane & 15;
  const int wr = wave >> 1, wc = wave & 1;
  int nt, mt, b, split;
  if (SYMM) {
    b = blockIdx.z; split = 0;
    int t = blockIdx.x, r = 0;
    while (t >= 32 - r) { t -= 32 - r; ++r; }
    mt = r; nt = r + t;
  } else {
    nt = blockIdx.x; mt = blockIdx.y;
    b = blockIdx.z & 1; split = blockIdx.z >> 1;
  }
  const int row0 = mt * BM, col0 = nt * BN;

  f32x4 acc[FM][FN];
  const f32x4 zero4 = {0.f, 0.f, 0.f, 0.f};
#pragma unroll
  for (int i = 0; i < FM; ++i)
#pragma unroll
    for (int j = 0; j < FN; ++j) acc[i][j] = zero4;

  constexpr int RA = BM / 64;
  constexpr int RB = BN / 64;

  const int s0 = split * args.segs_per_split;
  int s1 = s0 + args.segs_per_split;
  if (s1 > args.nseg) s1 = args.nseg;

  for (int s = s0; s < s1; ++s) {
    const u16_t* Abh = args.segs[s].Ah + (size_t)b * args.sA;
    const u16_t* Abl = args.segs[s].Al + (size_t)b * args.sA;
    const u16_t* Bbh = args.segs[s].Bh + (size_t)b * args.sB;
    const u16_t* Bbl = args.segs[s].Bl + (size_t)b * args.sB;
    const int boff = args.segs[s].boff;
    for (int k0 = 0; k0 < args.K; k0 += 32) {
      __syncthreads();
#pragma unroll
      for (int r = 0; r < RA; ++r) {
        int idx = (r * 4 + wave) * 64 + lane;
        int chunk = idx / BM, m = idx % BM;
        size_t goff = (size_t)(row0 + m) * args.ldA + (k0 + chunk * 8);
        gload_lds16(Abh + goff, aflat_h + (size_t)((r * 4 + wave) * 64) * 8);
        if (MODE == 0)
          gload_lds16(Abl + goff, aflat_l + (size_t)((r * 4 + wave) * 64) * 8);
      }
#pragma unroll
      for (int r = 0; r < RB; ++r) {
        int idx = (r * 4 + wave) * 64 + lane;
        int chunk = idx / BN, n = idx % BN;
        long long rowi;
        if (PADB) {
          int gn = col0 + n;
          rowi = (long long)((gn >> 6) + 1) * 66 + (gn & 63) + 1 + boff;
        } else {
          rowi = col0 + n;
        }
        size_t goff = (size_t)rowi * args.ldB + (k0 + chunk * 8);
        gload_lds16(Bbh + goff, bflat_h + (size_t)((r * 4 + wave) * 64) * 8);
        if (MODE <= 1)
          gload_lds16(Bbl + goff, bflat_l + (size_t)((r * 4 + wave) * 64) * 8);
      }
      __syncthreads();
      short8 afh[FM], afl[FM], bfh[FN], bfl[FN];
#pragma unroll
      for (int i = 0; i < FM; ++i) {
        afh[i] = *(const short8*)(aflat_h + ((size_t)lhi * BM + wr * (BM / 2) + i * 16 + llo) * 8);
        if (MODE == 0)
          afl[i] = *(const short8*)(aflat_l + ((size_t)lhi * BM + wr * (BM / 2) + i * 16 + llo) * 8);
      }
#pragma unroll
      for (int j = 0; j < FN; ++j) {
        bfh[j] = *(const short8*)(bflat_h + ((size_t)lhi * BN + wc * (BN / 2) + j * 16 + llo) * 8);
        if (MODE <= 1)
          bfl[j] = *(const short8*)(bflat_l + ((size_t)lhi * BN + wc * (BN / 2) + j * 16 + llo) * 8);
      }
#pragma unroll
      for (int i = 0; i < FM; ++i)
#pragma unroll
        for (int j = 0; j < FN; ++j) {
          f32x4 t = acc[i][j];
          if (MODE <= 1)
            t = __builtin_amdgcn_mfma_f32_16x16x32_bf16(afh[i], bfl[j], t, 0, 0, 0);
          if (MODE == 0)
            t = __builtin_amdgcn_mfma_f32_16x16x32_bf16(afl[i], bfh[j], t, 0, 0, 0);
          t = __builtin_amdgcn_mfma_f32_16x16x32_bf16(afh[i], bfh[j], t, 0, 0, 0);
          acc[i][j] = t;
        }
    }
  }

  float* outp = args.outf + (size_t)split * args.sSplit + (size_t)b * args.sOut;
#pragma unroll
  for (int i = 0; i < FM; ++i) {
    int mb = row0 + wr * (BM / 2) + i * 16 + lhi * 4;
#pragma unroll
    for (int j = 0; j < FN; ++j) {
      int n = col0 + wc * (BN / 2) + j * 16 + llo;
      f32x4 vv = acc[i][j] * args.alpha;
      *(f32x4*)(outp + (size_t)n * args.ldT + mb) = vv;
    }
  }
  if (SYMM) {
    if (nt != mt) {
      // Mirror block: rows m=row0.., cols n=col0.. — coalesced via LDS transpose.
      float* tb = (float*)smem;  // 32x132 f32 = 16.9KB, fits in staging smem
#pragma unroll
      for (int i = 0; i < FM; ++i) {
        __syncthreads();  // staging smem no longer read (all MFMA done)
#pragma unroll
        for (int j = 0; j < FN; ++j) {
#pragma unroll
          for (int r2 = 0; r2 < 4; ++r2) {
            int trow = wr * 16 + lhi * 4 + r2;
            int tcol = wc * 64 + j * 16 + llo;
            tb[trow * 132 + tcol] = acc[i][j][r2] * args.alpha;
          }
        }
        __syncthreads();
#pragma unroll
        for (int it = 0; it < 4; ++it) {
          int idx = it * 256 + tid;
          int row = idx >> 5, c4 = idx & 31;
          int mg = row0 + (row >> 4) * 64 + i * 16 + (row & 15);
          f32x4 v4 = *(f32x4*)&tb[row * 132 + c4 * 4];
          *(f32x4*)(outp + (size_t)mg * args.ldT + col0 + c4 * 4) = v4;
        }
      }
    }
  }
}

// Zero ONLY the 260 pad rows per batch of the padded xT layout (hi+lo bufs).
__global__ __launch_bounds__(256) void zeropad(u16_t* __restrict__ xh, u16_t* __restrict__ xl) {
  int rowi = blockIdx.x % 260;
  int b = blockIdx.x / 260;
  int rp;
  if (rowi < 66) rp = rowi;
  else if (rowi < 132) rp = 4290 + (rowi - 66);
  else { int g = (rowi - 132) >> 1; rp = (g + 1) * 66 + ((rowi - 132) & 1) * 65; }
  size_t base = ((size_t)b * 4356 + rp) * 512;
  int t = threadIdx.x;
  const us4 z = {0, 0, 0, 0};
  if (t < 128) *(us4*)(xh + base + (size_t)t * 4) = z;
  else *(us4*)(xl + base + (size_t)(t - 128) * 4) = z;
}

// Sum ns split-partials; apply (optional scale)*v+bias, relu; split-store bf16 hi/lo.
template<int LDT, bool PER_COL>
__global__ __launch_bounds__(256) void reduce_split(
    const float* __restrict__ part, long long sSplit, int ns,
    const float* __restrict__ scale, const float* __restrict__ bias,
    u16_t* __restrict__ oh, u16_t* __restrict__ ol, long long total) {
  long long i = ((long long)blockIdx.x * 256 + threadIdx.x) * 4;
  if (i >= total) return;
  f32x4 s = *(const f32x4*)(part + i);
  for (int p = 1; p < ns; ++p) s += *(const f32x4*)(part + (size_t)p * sSplit + i);
  f32x4 v;
  if (PER_COL) {
    int c = (int)(i & (LDT - 1));
    f32x4 bi = *(const f32x4*)(bias + c);
    if (scale) { f32x4 sc = *(const f32x4*)(scale + c); v = s * sc + bi; }
    else v = s + bi;
  } else {
    int r = (int)((i / LDT) & 255);
    float bi = bias[r];
    v = s + bi;
  }
  us4 h, l;
#pragma unroll
  for (int c2 = 0; c2 < 4; ++c2) {
    float vv = v[c2] > 0.f ? v[c2] : 0.f;
    u16_t hh = f2bf(vv);
    h[c2] = hh;
    l[c2] = f2bf(vv - bf2f(hh));
  }
  *(us4*)(oh + i) = h;
  if (ol) *(us4*)(ol + i) = l;
}

__global__ __launch_bounds__(256) void reduce_split_f32(
    const float* __restrict__ part, long long sSplit, int ns,
    float* __restrict__ out, long long total) {
  long long i = ((long long)blockIdx.x * 256 + threadIdx.x) * 4;
  if (i >= total) return;
  f32x4 s = *(const f32x4*)(part + i);
  for (int p = 1; p < ns; ++p) s += *(const f32x4*)(part + (size_t)p * sSplit + i);
  *(f32x4*)(out + i) = s;
}

// Row softmax over 4096, in-place fp32 + bf16 copy for PV.
__global__ __launch_bounds__(256) void softmax_k(float* S, u16_t* P) {
  const int row = blockIdx.x;
  float* Sr = S + (size_t)row * 4096;
  u16_t* Pr = P + (size_t)row * 4096;
  const int t = threadIdx.x;
  const int wave = t >> 6;
  f32x4 v[4];
  float vmax = -3.4e38f;
#pragma unroll
  for (int i = 0; i < 4; ++i) {
    v[i] = ((const f32x4*)Sr)[t + i * 256];
#pragma unroll
    for (int c = 0; c < 4; ++c) vmax = fmaxf(vmax, v[i][c]);
  }
#pragma unroll
  for (int off = 32; off; off >>= 1) vmax = fmaxf(vmax, __shfl_xor(vmax, off));
  __shared__ float red[4];
  if ((t & 63) == 0) red[wave] = vmax;
  __syncthreads();
  vmax = fmaxf(fmaxf(red[0], red[1]), fmaxf(red[2], red[3]));
  float sum = 0.f;
#pragma unroll
  for (int i = 0; i < 4; ++i)
#pragma unroll
    for (int c = 0; c < 4; ++c) { v[i][c] = __expf(v[i][c] - vmax); sum += v[i][c]; }
#pragma unroll
  for (int off = 32; off; off >>= 1) sum += __shfl_xor(sum, off);
  __shared__ float red2[4];
  if ((t & 63) == 0) red2[wave] = sum;
  __syncthreads();
  sum = red2[0] + red2[1] + red2[2] + red2[3];
  float rs = 1.0f / sum;
#pragma unroll
  for (int i = 0; i < 4; ++i) {
    f32x4 o = v[i] * rs;
    ((f32x4*)Sr)[t + i * 256] = o;
    us4 pb;
#pragma unroll
    for (int c = 0; c < 4; ++c) pb[c] = f2bf(o[c]);
    ((us4*)Pr)[t + i * 256] = pb;
  }
}

// x [2][512][4096] -> padded transposed split xT [2][4356][512] (hi/lo bf16).
__global__ __launch_bounds__(256) void xprep(const float* __restrict__ x,
                                             u16_t* __restrict__ xh, u16_t* __restrict__ xl) {
  __shared__ float tile[64][65];
  const int b = blockIdx.z, c0 = blockIdx.y * 64, n0 = blockIdx.x * 64;
  const float* xb = x + ((size_t)b * 512 + c0) * 4096 + n0;
  const int t = threadIdx.x;
  const int tr = t >> 6, tc = t & 63;
#pragma unroll
  for (int rr = 0; rr < 16; ++rr) {
    int ci = tr + rr * 4;
    tile[ci][tc] = xb[(size_t)ci * 4096 + tc];
  }
  __syncthreads();
#pragma unroll
  for (int rr = 0; rr < 16; ++rr) {
    int nj = rr * 4 + tr;
    float v = tile[tc][nj];
    size_t rp = (size_t)(blockIdx.x + 1) * 66 + nj + 1;
    size_t o = ((size_t)b * 4356 + rp) * 512 + c0 + tc;
    u16_t hh = f2bf(v);
    xh[o] = hh;
    xl[o] = f2bf(v - bf2f(hh));
  }
}

// Fused weight prep: bnprep (256) | wk split (131072) | wv2 split (65536) |
// wv1 remap->w1h only (1179648)
__global__ __launch_bounds__(256) void prep_all(
    const float* __restrict__ wk, const float* __restrict__ wv2, const float* __restrict__ wv1,
    const float* __restrict__ g, const float* __restrict__ be, const float* __restrict__ mu,
    const float* __restrict__ var, const float* __restrict__ bkb,
    u16_t* __restrict__ wkh, u16_t* __restrict__ wkl,
    u16_t* __restrict__ w2h, u16_t* __restrict__ w2l,
    u16_t* __restrict__ w1h, float* __restrict__ bnA, float* __restrict__ bnB) {
  long long i = (long long)blockIdx.x * 256 + threadIdx.x;
  if (i < 256) {
    float s = g[i] * rsqrtf(var[i] + 1e-5f);
    bnA[i] = s;
    bnB[i] = (bkb[i] - mu[i]) * s + be[i];
    return;
  }
  i -= 256;
  if (i < 131072) {
    float v = wk[i];
    u16_t hh = f2bf(v);
    wkh[i] = hh; wkl[i] = f2bf(v - bf2f(hh));
    return;
  }
  i -= 131072;
  if (i < 65536) {
    float v = wv2[i];
    u16_t hh = f2bf(v);
    w2h[i] = hh; w2l[i] = f2bf(v - bf2f(hh));
    return;
  }
  i -= 65536;
  if (i < 1179648) {
    int tp = (int)(i / (256 * 512));
    int rem = (int)(i % (256 * 512));
    int o = rem / 512, c = rem % 512;
    w1h[i] = f2bf(wv1[((size_t)o * 512 + c) * 9 + tp]);
  }
}

extern "C" void kernel_launch(void* const* d_in, const int* in_sizes, int n_in,
                              void* d_out, int out_size, void* d_ws, size_t ws_size,
                              hipStream_t stream) {
  (void)in_sizes; (void)n_in; (void)out_size; (void)ws_size;
  const float* x   = (const float*)d_in[0];
  const float* wk  = (const float*)d_in[1];
  const float* bk  = (const float*)d_in[2];
  const float* gam = (const float*)d_in[3];
  const float* bet = (const float*)d_in[4];
  const float* mu  = (const float*)d_in[5];
  const float* var = (const float*)d_in[6];
  const float* wv1 = (const float*)d_in[7];
  const float* bv1 = (const float*)d_in[8];
  const float* wv2 = (const float*)d_in[9];
  const float* bv2 = (const float*)d_in[10];

  const int B = 2;
  const size_t XT_E  = (size_t)B * 4356 * 512;
  const size_t WK_E  = 256 * 512;
  const size_t WV1_E = 9ull * 256 * 512;
  const size_t WV2_E = 256 * 256;
  const size_t FT_E  = (size_t)B * 4096 * 256;   // 2,097,152
  const size_t P_E   = (size_t)B * 4096 * 4096;

  size_t off = 0;
  auto carve = [&](size_t bytes) -> char* {
    off = (off + 255) & ~(size_t)255;
    char* p = (char*)d_ws + off;
    off += bytes;
    return p;
  };
  u16_t* xh  = (u16_t*)carve(XT_E * 2);
  u16_t* xl  = (u16_t*)carve(XT_E * 2);
  u16_t* wkh = (u16_t*)carve(WK_E * 2);
  u16_t* wkl = (u16_t*)carve(WK_E * 2);
  u16_t* w1h = (u16_t*)carve(WV1_E * 2);
  u16_t* w1l = (u16_t*)carve(WV1_E * 2);   // unused (conv is MODE2)
  u16_t* w2h = (u16_t*)carve(WV2_E * 2);
  u16_t* w2l = (u16_t*)carve(WV2_E * 2);
  u16_t* fth = (u16_t*)carve(FT_E * 2);
  u16_t* ftl = (u16_t*)carve(FT_E * 2);
  u16_t* v1h = (u16_t*)carve(FT_E * 2);
  u16_t* v1l = (u16_t*)carve(FT_E * 2);
  u16_t* vh  = (u16_t*)carve(FT_E * 2);
  u16_t* vl  = (u16_t*)carve(FT_E * 2);    // unused
  u16_t* Pb  = (u16_t*)carve(P_E * 2);
  float* bnA = (float*)carve(256 * 4);
  float* bnB = (float*)carve(256 * 4);

  // Aliased scratch (lifetimes verified):
  //  big_part (Pb region): feat (2x8.4MB) / conv (5x8.4MB) / wv2 (2x8.4MB)
  //            partials; all complete before softmax writes Pb.
  //  pv_part (ws start): PV partials 4x8.4 = 33.5MB; everything below 33.5MB
  //            offset (xh..fth..) is dead by PV time and rewritten per call.
  //            vh at ~44.3MB, Pb at ~48.5MB: beyond partials.
  float* big_part = (float*)Pb;
  float* pv_part  = (float*)d_ws;

  float* ctx = (float*)d_out;                          // [2][256][4096]
  float* sim = (float*)d_out + (size_t)B * 256 * 4096; // [2][4096][4096]

  const long long FT_LL = (long long)FT_E;

  zeropad<<<520, 256, 0, stream>>>(xh, xl);
  prep_all<<<5377, 256, 0, stream>>>(wk, wv2, wv1, gam, bet, mu, var, bk,
                                     wkh, wkl, w2h, w2l, w1h, bnA, bnB);
  xprep<<<dim3(64, 8, 2), 256, 0, stream>>>(x, xh, xl);

  // ---- feat = relu(BN(wk @ x)): fused hi/lo MODE0, 2 K-splits of 256
  {
    GemmArgs a = {};
    a.segs[0] = {wkh,       wkl,       xh,       xl,       0};
    a.segs[1] = {wkh + 256, wkl + 256, xh + 256, xl + 256, 0};
    a.nseg = 2; a.segs_per_split = 1; a.K = 256; a.ldA = 512; a.ldB = 512;
    a.sA = 0; a.sB = (long long)4356 * 512; a.alpha = 1.f;
    a.outf = big_part; a.sOut = (long long)4096 * 256; a.sSplit = FT_LL; a.ldT = 256;
    gemm_tn<64, 128, 0, true, false><<<dim3(32, 4, 4), 256, 0, stream>>>(a);
    reduce_split<256, true><<<2048, 256, 0, stream>>>(big_part, FT_LL, 2, bnA, bnB, fth, ftl, FT_LL);
  }
  // ---- QK: S = fth @ (fth+ftl)^T * Ck^-0.5, MODE1, symmetric upper-triangle
  {
    GemmArgs a = {};
    a.segs[0] = {fth, nullptr, fth, ftl, 0};
    a.nseg = 1; a.segs_per_split = 1; a.K = 256; a.ldA = 256; a.ldB = 256;
    a.sA = (long long)4096 * 256; a.sB = (long long)4096 * 256; a.alpha = 0.0625f;
    a.outf = sim; a.sOut = (long long)4096 * 4096; a.sSplit = 0; a.ldT = 4096;
    gemm_tn<128, 128, 1, false, true><<<dim3(528, 1, 2), 256, 0, stream>>>(a);
  }
  // ---- conv3x3 + bias + relu -> v1T: 9 taps, 2 taps/split (5 splits), MODE2
  {
    GemmArgs a = {};
    for (int ty = 0; ty < 3; ++ty)
      for (int tx = 0; tx < 3; ++tx) {
        int tp = ty * 3 + tx;
        int boff = (ty - 1) * 66 + (tx - 1);
        a.segs[tp] = {w1h + (size_t)tp * 131072, nullptr, xh, nullptr, boff};
      }
    a.nseg = 9; a.segs_per_split = 2; a.K = 512; a.ldA = 512; a.ldB = 512;
    a.sA = 0; a.sB = (long long)4356 * 512; a.alpha = 1.f;
    a.outf = big_part; a.sOut = (long long)4096 * 256; a.sSplit = FT_LL; a.ldT = 256;
    gemm_tn<128, 128, 2, true, false><<<dim3(32, 2, 10), 256, 0, stream>>>(a);
    reduce_split<256, true><<<2048, 256, 0, stream>>>(big_part, FT_LL, 5, nullptr, bv1, v1h, v1l, FT_LL);
  }
  // ---- v = relu(wv2 @ v1 + bv2), flipped (M=4096, N=256), MODE0, 2 K-splits
  {
    GemmArgs a = {};
    a.segs[0] = {v1h,       v1l,       w2h,       w2l,       0};
    a.segs[1] = {v1h + 128, v1l + 128, w2h + 128, w2l + 128, 0};
    a.nseg = 2; a.segs_per_split = 1; a.K = 128; a.ldA = 256; a.ldB = 256;
    a.sA = (long long)4096 * 256; a.sB = 0; a.alpha = 1.f;
    a.outf = big_part; a.sOut = (long long)256 * 4096; a.sSplit = FT_LL; a.ldT = 4096;
    gemm_tn<128, 64, 0, false, false><<<dim3(4, 32, 4), 256, 0, stream>>>(a);
    reduce_split<4096, false><<<2048, 256, 0, stream>>>(big_part, FT_LL, 2, nullptr, bv2, vh, nullptr, FT_LL);
  }
  softmax_k<<<B * 4096, 256, 0, stream>>>(sim, Pb);
  // ---- ctx = P @ v^T: MODE2 (P bf16 exact, v_h only), 4 K-splits of 1024
  {
    GemmArgs a = {};
    for (int q = 0; q < 4; ++q)
      a.segs[q] = {Pb + (size_t)q * 1024, nullptr, vh + (size_t)q * 1024, nullptr, 0};
    a.nseg = 4; a.segs_per_split = 1; a.K = 1024; a.ldA = 4096; a.ldB = 4096;
    a.sA = (long long)4096 * 4096; a.sB = (long long)256 * 4096; a.alpha = 1.f;
    a.outf = pv_part; a.sOut = (long long)256 * 4096; a.sSplit = FT_LL; a.ldT = 4096;
    gemm_tn<128, 128, 2, false, false><<<dim3(2, 32, 8), 256, 0, stream>>>(a);
    reduce_split_f32<<<2048, 256, 0, stream>>>(pv_part, FT_LL, 4, ctx, FT_LL);
  }
  (void)vl; (void)w1l;
}

// Round 7
// 265.943 us; speedup vs baseline: 2.6099x; 1.0571x over previous
//
#include <hip/hip_runtime.h>
#include <hip/hip_bf16.h>
#include <stdint.h>

typedef unsigned short u16_t;
typedef __attribute__((ext_vector_type(8))) short short8;
typedef __attribute__((ext_vector_type(4))) float f32x4;
typedef __attribute__((ext_vector_type(4))) unsigned short us4;

__device__ __forceinline__ float bf2f(u16_t u) {
  union { unsigned int i; float f; } c; c.i = ((unsigned int)u) << 16; return c.f;
}
__device__ __forceinline__ u16_t f2bf(float f) {
  union { float f; unsigned int i; } c; c.f = f;
  unsigned int x = c.i;
  unsigned int r = x + 0x7fffu + ((x >> 16) & 1u);
  return (u16_t)(r >> 16);
}

__device__ __forceinline__ void gload_lds16(const u16_t* g, u16_t* l) {
  __builtin_amdgcn_global_load_lds(
      (const __attribute__((address_space(1))) void*)g,
      (__attribute__((address_space(3))) void*)(unsigned int)(uintptr_t)l,
      16, 0, 0);
}

struct Seg {
  const u16_t* Ah;
  const u16_t* Al;
  const u16_t* Bh;
  const u16_t* Bl;
  int boff;
};

struct GemmArgs {
  Seg segs[9];
  int nseg;
  int segs_per_split;
  int K;
  int ldA, ldB;
  long long sA, sB;
  float alpha;
  float* outf;
  long long sOut;
  long long sSplit;
  int ldT;
};

// Fused-split TN GEMM.  MODE 0: Ah*Bh+Al*Bh+Ah*Bl; 1: Ah*Bh+Ah*Bl; 2: Ah*Bh.
// NCH = k-chunks (of 8) staged per barrier pair (4 -> K_STEP 32, 8 -> 64).
// fp32 transposed store; SYMM: upper-triangle + coalesced mirror via LDS.
template<int BM, int BN, int MODE, bool PADB, bool SYMM, int NCH = 4>
__global__ __launch_bounds__(256, 4) void gemm_tn(GemmArgs args) {
  constexpr int FM = BM / 32, FN = BN / 32;
  constexpr int AH_E = NCH * BM * 8;
  constexpr int AL_E = (MODE == 0) ? NCH * BM * 8 : 8;
  constexpr int BH_E = NCH * BN * 8;
  constexpr int BL_E = (MODE <= 1) ? NCH * BN * 8 : 8;
  constexpr int SM_E = AH_E + AL_E + BH_E + BL_E;
  static_assert(!SYMM || (size_t)SM_E * 2 >= 32 * 132 * 4, "tbuf alias too small");
  __shared__ __align__(16) u16_t smem[SM_E];
  u16_t* aflat_h = smem;
  u16_t* aflat_l = smem + AH_E;
  u16_t* bflat_h = smem + AH_E + AL_E;
  u16_t* bflat_l = smem + AH_E + AL_E + BH_E;

  const int tid = threadIdx.x;
  const int wave = tid >> 6, lane = tid & 63;
  const int lhi = lane >> 4, llo = lane & 15;
  const int wr = wave >> 1, wc = wave & 1;
  int nt, mt, b, split;
  if (SYMM) {
    b = blockIdx.z; split = 0;
    int t = blockIdx.x, r = 0;
    while (t >= 32 - r) { t -= 32 - r; ++r; }
    mt = r; nt = r + t;
  } else {
    nt = blockIdx.x; mt = blockIdx.y;
    b = blockIdx.z & 1; split = blockIdx.z >> 1;
  }
  const int row0 = mt * BM, col0 = nt * BN;

  f32x4 acc[FM][FN];
  const f32x4 zero4 = {0.f, 0.f, 0.f, 0.f};
#pragma unroll
  for (int i = 0; i < FM; ++i)
#pragma unroll
    for (int j = 0; j < FN; ++j) acc[i][j] = zero4;

  constexpr int RA = BM * NCH / 256;
  constexpr int RB = BN * NCH / 256;

  const int s0 = split * args.segs_per_split;
  int s1 = s0 + args.segs_per_split;
  if (s1 > args.nseg) s1 = args.nseg;

  for (int s = s0; s < s1; ++s) {
    const u16_t* Abh = args.segs[s].Ah + (size_t)b * args.sA;
    const u16_t* Abl = args.segs[s].Al + (size_t)b * args.sA;
    const u16_t* Bbh = args.segs[s].Bh + (size_t)b * args.sB;
    const u16_t* Bbl = args.segs[s].Bl + (size_t)b * args.sB;
    const int boff = args.segs[s].boff;
    for (int k0 = 0; k0 < args.K; k0 += NCH * 8) {
      __syncthreads();
#pragma unroll
      for (int r = 0; r < RA; ++r) {
        int idx = r * 256 + tid;
        int chunk = idx / BM, m = idx % BM;
        size_t goff = (size_t)(row0 + m) * args.ldA + (k0 + chunk * 8);
        gload_lds16(Abh + goff, aflat_h + (size_t)idx * 8);
        if (MODE == 0)
          gload_lds16(Abl + goff, aflat_l + (size_t)idx * 8);
      }
#pragma unroll
      for (int r = 0; r < RB; ++r) {
        int idx = r * 256 + tid;
        int chunk = idx / BN, n = idx % BN;
        long long rowi;
        if (PADB) {
          int gn = col0 + n;
          rowi = (long long)((gn >> 6) + 1) * 66 + (gn & 63) + 1 + boff;
        } else {
          rowi = col0 + n;
        }
        size_t goff = (size_t)rowi * args.ldB + (k0 + chunk * 8);
        gload_lds16(Bbh + goff, bflat_h + (size_t)idx * 8);
        if (MODE <= 1)
          gload_lds16(Bbl + goff, bflat_l + (size_t)idx * 8);
      }
      __syncthreads();
#pragma unroll
      for (int kk = 0; kk < NCH / 4; ++kk) {
        const int ckA = (kk * 4 + lhi) * BM;
        const int ckB = (kk * 4 + lhi) * BN;
        short8 afh[FM], afl[FM], bfh[FN], bfl[FN];
#pragma unroll
        for (int i = 0; i < FM; ++i) {
          afh[i] = *(const short8*)(aflat_h + ((size_t)ckA + wr * (BM / 2) + i * 16 + llo) * 8);
          if (MODE == 0)
            afl[i] = *(const short8*)(aflat_l + ((size_t)ckA + wr * (BM / 2) + i * 16 + llo) * 8);
        }
#pragma unroll
        for (int j = 0; j < FN; ++j) {
          bfh[j] = *(const short8*)(bflat_h + ((size_t)ckB + wc * (BN / 2) + j * 16 + llo) * 8);
          if (MODE <= 1)
            bfl[j] = *(const short8*)(bflat_l + ((size_t)ckB + wc * (BN / 2) + j * 16 + llo) * 8);
        }
#pragma unroll
        for (int i = 0; i < FM; ++i)
#pragma unroll
          for (int j = 0; j < FN; ++j) {
            f32x4 t = acc[i][j];
            if (MODE <= 1)
              t = __builtin_amdgcn_mfma_f32_16x16x32_bf16(afh[i], bfl[j], t, 0, 0, 0);
            if (MODE == 0)
              t = __builtin_amdgcn_mfma_f32_16x16x32_bf16(afl[i], bfh[j], t, 0, 0, 0);
            t = __builtin_amdgcn_mfma_f32_16x16x32_bf16(afh[i], bfh[j], t, 0, 0, 0);
            acc[i][j] = t;
          }
      }
    }
  }

  float* outp = args.outf + (size_t)split * args.sSplit + (size_t)b * args.sOut;
#pragma unroll
  for (int i = 0; i < FM; ++i) {
    int mb = row0 + wr * (BM / 2) + i * 16 + lhi * 4;
#pragma unroll
    for (int j = 0; j < FN; ++j) {
      int n = col0 + wc * (BN / 2) + j * 16 + llo;
      f32x4 vv = acc[i][j] * args.alpha;
      *(f32x4*)(outp + (size_t)n * args.ldT + mb) = vv;
    }
  }
  if (SYMM) {
    if (nt != mt) {
      float* tb = (float*)smem;  // 32x132 f32, aliases staging smem post-K-loop
#pragma unroll
      for (int i = 0; i < FM; ++i) {
        __syncthreads();
#pragma unroll
        for (int j = 0; j < FN; ++j) {
#pragma unroll
          for (int r2 = 0; r2 < 4; ++r2) {
            int trow = wr * 16 + lhi * 4 + r2;
            int tcol = wc * 64 + j * 16 + llo;
            tb[trow * 132 + tcol] = acc[i][j][r2] * args.alpha;
          }
        }
        __syncthreads();
#pragma unroll
        for (int it = 0; it < 4; ++it) {
          int idx = it * 256 + tid;
          int row = idx >> 5, c4 = idx & 31;
          int mg = row0 + (row >> 4) * 64 + i * 16 + (row & 15);
          f32x4 v4 = *(f32x4*)&tb[row * 132 + c4 * 4];
          *(f32x4*)(outp + (size_t)mg * args.ldT + col0 + c4 * 4) = v4;
        }
      }
    }
  }
}

// Conv3x3 as 3 ty-splits; the 3 tx taps share ONE staged B tile with halo.
// Padded row for (gn, ty, tx): (2nt+ty)*66 + (n>>6)*66 + (n&63) + tx  (tx in 0..2)
// => stage 144 contiguous rows from base=(2nt+ty)*66; fragments read r<=131.
struct Conv3Args {
  const u16_t* W;      // w1h [9][256][512]
  const u16_t* X;      // xh  [2][4356][512] (padded)
  float* outf;
  long long sOut;      // batch stride
  long long sSplit;    // split (ty) stride
};
__global__ __launch_bounds__(256, 4) void conv3_gemm(Conv3Args a) {
  __shared__ __align__(16) u16_t lA[3][4][128][8];  // 24KB
  __shared__ __align__(16) u16_t lB[4 * 144 * 8];   // 9.2KB
  const int tid = threadIdx.x;
  const int wave = tid >> 6, lane = tid & 63;
  const int lhi = lane >> 4, llo = lane & 15;
  const int wr = wave >> 1, wc = wave & 1;
  const int nt = blockIdx.x, mt = blockIdx.y;
  const int b = blockIdx.z & 1, ty = blockIdx.z >> 1;
  const int row0 = mt * 128;
  const int base = (2 * nt + ty) * 66;
  const u16_t* Xb = a.X + (size_t)b * 4356 * 512;
  const u16_t* Wt = a.W + (size_t)(ty * 3) * 131072;

  f32x4 acc[4][4];
  const f32x4 zero4 = {0.f, 0.f, 0.f, 0.f};
#pragma unroll
  for (int i = 0; i < 4; ++i)
#pragma unroll
    for (int j = 0; j < 4; ++j) acc[i][j] = zero4;

  for (int k0 = 0; k0 < 512; k0 += 32) {
    __syncthreads();
#pragma unroll
    for (int t = 0; t < 3; ++t)
#pragma unroll
      for (int r = 0; r < 2; ++r) {
        int slot = r * 256 + tid;
        int chunk = slot >> 7, m = slot & 127;
        const u16_t* src = Wt + (size_t)t * 131072 + (size_t)(row0 + m) * 512 + k0 + chunk * 8;
        gload_lds16(src, &lA[t][0][0][0] + (size_t)slot * 8);
      }
#pragma unroll
    for (int r = 0; r < 2; ++r) {
      int idx = r * 256 + tid;
      int chunk = idx / 144, rr = idx % 144;
      gload_lds16(Xb + (size_t)(base + rr) * 512 + k0 + chunk * 8, lB + (size_t)idx * 8);
    }
    if (tid < 64) {
      int idx = 512 + tid;
      int chunk = idx / 144, rr = idx % 144;
      gload_lds16(Xb + (size_t)(base + rr) * 512 + k0 + chunk * 8, lB + (size_t)idx * 8);
    }
    __syncthreads();
#pragma unroll
    for (int t = 0; t < 3; ++t) {
      short8 af[4], bf[4];
#pragma unroll
      for (int i = 0; i < 4; ++i)
        af[i] = *(const short8*)&lA[t][lhi][wr * 64 + i * 16 + llo][0];
#pragma unroll
      for (int j = 0; j < 4; ++j) {
        int rB = wc * 66 + j * 16 + llo + t;
        bf[j] = *(const short8*)(lB + ((size_t)lhi * 144 + rB) * 8);
      }
#pragma unroll
      for (int i = 0; i < 4; ++i)
#pragma unroll
        for (int j = 0; j < 4; ++j)
          acc[i][j] = __builtin_amdgcn_mfma_f32_16x16x32_bf16(af[i], bf[j], acc[i][j], 0, 0, 0);
    }
  }

  float* outp = a.outf + (size_t)ty * a.sSplit + (size_t)b * a.sOut;
#pragma unroll
  for (int i = 0; i < 4; ++i) {
    int mb = row0 + wr * 64 + i * 16 + lhi * 4;
#pragma unroll
    for (int j = 0; j < 4; ++j) {
      int n = (nt << 7) + wc * 64 + j * 16 + llo;
      *(f32x4*)(outp + (size_t)n * 256 + mb) = acc[i][j];
    }
  }
}

// Sum ns split-partials; apply (optional scale)*v+bias, relu; split-store bf16 hi/lo.
template<int LDT, bool PER_COL>
__global__ __launch_bounds__(256) void reduce_split(
    const float* __restrict__ part, long long sSplit, int ns,
    const float* __restrict__ scale, const float* __restrict__ bias,
    u16_t* __restrict__ oh, u16_t* __restrict__ ol, long long total) {
  long long i = ((long long)blockIdx.x * 256 + threadIdx.x) * 4;
  if (i >= total) return;
  f32x4 s = *(const f32x4*)(part + i);
  for (int p = 1; p < ns; ++p) s += *(const f32x4*)(part + (size_t)p * sSplit + i);
  f32x4 v;
  if (PER_COL) {
    int c = (int)(i & (LDT - 1));
    f32x4 bi = *(const f32x4*)(bias + c);
    if (scale) { f32x4 sc = *(const f32x4*)(scale + c); v = s * sc + bi; }
    else v = s + bi;
  } else {
    int r = (int)((i / LDT) & 255);
    float bi = bias[r];
    v = s + bi;
  }
  us4 h, l;
#pragma unroll
  for (int c2 = 0; c2 < 4; ++c2) {
    float vv = v[c2] > 0.f ? v[c2] : 0.f;
    u16_t hh = f2bf(vv);
    h[c2] = hh;
    l[c2] = f2bf(vv - bf2f(hh));
  }
  *(us4*)(oh + i) = h;
  if (ol) *(us4*)(ol + i) = l;
}

__global__ __launch_bounds__(256) void reduce_split_f32(
    const float* __restrict__ part, long long sSplit, int ns,
    float* __restrict__ out, long long total) {
  long long i = ((long long)blockIdx.x * 256 + threadIdx.x) * 4;
  if (i >= total) return;
  f32x4 s = *(const f32x4*)(part + i);
  for (int p = 1; p < ns; ++p) s += *(const f32x4*)(part + (size_t)p * sSplit + i);
  *(f32x4*)(out + i) = s;
}

// Row softmax over 4096, in-place fp32 + bf16 copy for PV.
__global__ __launch_bounds__(256) void softmax_k(float* S, u16_t* P) {
  const int row = blockIdx.x;
  float* Sr = S + (size_t)row * 4096;
  u16_t* Pr = P + (size_t)row * 4096;
  const int t = threadIdx.x;
  const int wave = t >> 6;
  f32x4 v[4];
  float vmax = -3.4e38f;
#pragma unroll
  for (int i = 0; i < 4; ++i) {
    v[i] = ((const f32x4*)Sr)[t + i * 256];
#pragma unroll
    for (int c = 0; c < 4; ++c) vmax = fmaxf(vmax, v[i][c]);
  }
#pragma unroll
  for (int off = 32; off; off >>= 1) vmax = fmaxf(vmax, __shfl_xor(vmax, off));
  __shared__ float red[4];
  if ((t & 63) == 0) red[wave] = vmax;
  __syncthreads();
  vmax = fmaxf(fmaxf(red[0], red[1]), fmaxf(red[2], red[3]));
  float sum = 0.f;
#pragma unroll
  for (int i = 0; i < 4; ++i)
#pragma unroll
    for (int c = 0; c < 4; ++c) { v[i][c] = __expf(v[i][c] - vmax); sum += v[i][c]; }
#pragma unroll
  for (int off = 32; off; off >>= 1) sum += __shfl_xor(sum, off);
  __shared__ float red2[4];
  if ((t & 63) == 0) red2[wave] = sum;
  __syncthreads();
  sum = red2[0] + red2[1] + red2[2] + red2[3];
  float rs = 1.0f / sum;
#pragma unroll
  for (int i = 0; i < 4; ++i) {
    f32x4 o = v[i] * rs;
    ((f32x4*)Sr)[t + i * 256] = o;
    us4 pb;
#pragma unroll
    for (int c = 0; c < 4; ++c) pb[c] = f2bf(o[c]);
    ((us4*)Pr)[t + i * 256] = pb;
  }
}

// x [2][512][4096] -> padded transposed split xT [2][4356][512] (hi/lo bf16).
__global__ __launch_bounds__(256) void xprep(const float* __restrict__ x,
                                             u16_t* __restrict__ xh, u16_t* __restrict__ xl) {
  __shared__ float tile[64][65];
  const int b = blockIdx.z, c0 = blockIdx.y * 64, n0 = blockIdx.x * 64;
  const float* xb = x + ((size_t)b * 512 + c0) * 4096 + n0;
  const int t = threadIdx.x;
  const int tr = t >> 6, tc = t & 63;
#pragma unroll
  for (int rr = 0; rr < 16; ++rr) {
    int ci = tr + rr * 4;
    tile[ci][tc] = xb[(size_t)ci * 4096 + tc];
  }
  __syncthreads();
#pragma unroll
  for (int rr = 0; rr < 16; ++rr) {
    int nj = rr * 4 + tr;
    float v = tile[tc][nj];
    size_t rp = (size_t)(blockIdx.x + 1) * 66 + nj + 1;
    size_t o = ((size_t)b * 4356 + rp) * 512 + c0 + tc;
    u16_t hh = f2bf(v);
    xh[o] = hh;
    xl[o] = f2bf(v - bf2f(hh));
  }
}

// Fused prep: bn (256) | wk split (131072) | wv2 split (65536) |
// wv1 remap (1179648) | zeropad (133120)
__global__ __launch_bounds__(256) void prep_all(
    const float* __restrict__ wk, const float* __restrict__ wv2, const float* __restrict__ wv1,
    const float* __restrict__ g, const float* __restrict__ be, const float* __restrict__ mu,
    const float* __restrict__ var, const float* __restrict__ bkb,
    u16_t* __restrict__ wkh, u16_t* __restrict__ wkl,
    u16_t* __restrict__ w2h, u16_t* __restrict__ w2l,
    u16_t* __restrict__ w1h, float* __restrict__ bnA, float* __restrict__ bnB,
    u16_t* __restrict__ xh, u16_t* __restrict__ xl) {
  long long i = (long long)blockIdx.x * 256 + threadIdx.x;
  if (i < 256) {
    float s = g[i] * rsqrtf(var[i] + 1e-5f);
    bnA[i] = s;
    bnB[i] = (bkb[i] - mu[i]) * s + be[i];
    return;
  }
  i -= 256;
  if (i < 131072) {
    float v = wk[i];
    u16_t hh = f2bf(v);
    wkh[i] = hh; wkl[i] = f2bf(v - bf2f(hh));
    return;
  }
  i -= 131072;
  if (i < 65536) {
    float v = wv2[i];
    u16_t hh = f2bf(v);
    w2h[i] = hh; w2l[i] = f2bf(v - bf2f(hh));
    return;
  }
  i -= 65536;
  if (i < 1179648) {
    int tp = (int)(i / (256 * 512));
    int rem = (int)(i % (256 * 512));
    int o = rem / 512, c = rem % 512;
    w1h[i] = f2bf(wv1[((size_t)o * 512 + c) * 9 + tp]);
    return;
  }
  i -= 1179648;
  if (i < 133120) {
    int blk = (int)(i >> 8), t = (int)(i & 255);
    int rowi = blk % 260, b = blk / 260;
    int rp;
    if (rowi < 66) rp = rowi;
    else if (rowi < 132) rp = 4290 + (rowi - 66);
    else { int g2 = (rowi - 132) >> 1; rp = (g2 + 1) * 66 + ((rowi - 132) & 1) * 65; }
    size_t base = ((size_t)b * 4356 + rp) * 512;
    const us4 z = {0, 0, 0, 0};
    if (t < 128) *(us4*)(xh + base + (size_t)t * 4) = z;
    else *(us4*)(xl + base + (size_t)(t - 128) * 4) = z;
  }
}

extern "C" void kernel_launch(void* const* d_in, const int* in_sizes, int n_in,
                              void* d_out, int out_size, void* d_ws, size_t ws_size,
                              hipStream_t stream) {
  (void)in_sizes; (void)n_in; (void)out_size; (void)ws_size;
  const float* x   = (const float*)d_in[0];
  const float* wk  = (const float*)d_in[1];
  const float* bk  = (const float*)d_in[2];
  const float* gam = (const float*)d_in[3];
  const float* bet = (const float*)d_in[4];
  const float* mu  = (const float*)d_in[5];
  const float* var = (const float*)d_in[6];
  const float* wv1 = (const float*)d_in[7];
  const float* bv1 = (const float*)d_in[8];
  const float* wv2 = (const float*)d_in[9];
  const float* bv2 = (const float*)d_in[10];

  const int B = 2;
  const size_t XT_E  = (size_t)B * 4356 * 512;
  const size_t WK_E  = 256 * 512;
  const size_t WV1_E = 9ull * 256 * 512;
  const size_t WV2_E = 256 * 256;
  const size_t FT_E  = (size_t)B * 4096 * 256;
  const size_t P_E   = (size_t)B * 4096 * 4096;

  size_t off = 0;
  auto carve = [&](size_t bytes) -> char* {
    off = (off + 255) & ~(size_t)255;
    char* p = (char*)d_ws + off;
    off += bytes;
    return p;
  };
  u16_t* xh  = (u16_t*)carve(XT_E * 2);
  u16_t* xl  = (u16_t*)carve(XT_E * 2);  // also absorbs conv3's 12-row stage overrun
  u16_t* wkh = (u16_t*)carve(WK_E * 2);
  u16_t* wkl = (u16_t*)carve(WK_E * 2);
  u16_t* w1h = (u16_t*)carve(WV1_E * 2);
  u16_t* w2h = (u16_t*)carve(WV2_E * 2);
  u16_t* w2l = (u16_t*)carve(WV2_E * 2);
  u16_t* fth = (u16_t*)carve(FT_E * 2);
  u16_t* ftl = (u16_t*)carve(FT_E * 2);
  u16_t* v1h = (u16_t*)carve(FT_E * 2);
  u16_t* v1l = (u16_t*)carve(FT_E * 2);
  u16_t* vh  = (u16_t*)carve(FT_E * 2);
  u16_t* Pb  = (u16_t*)carve(P_E * 2);
  float* bnA = (float*)carve(256 * 4);
  float* bnB = (float*)carve(256 * 4);

  // Aliased scratch: big_part (Pb region) for feat/conv/wv2 partials (max
  // 3x8.4MB < 134MB), all dead before softmax writes Pb. pv_part (ws start)
  // 33.5MB over xh..fth region, all dead by PV time, rewritten per call.
  float* big_part = (float*)Pb;
  float* pv_part  = (float*)d_ws;

  float* ctx = (float*)d_out;
  float* sim = (float*)d_out + (size_t)B * 256 * 4096;

  const long long FT_LL = (long long)FT_E;

  prep_all<<<5897, 256, 0, stream>>>(wk, wv2, wv1, gam, bet, mu, var, bk,
                                     wkh, wkl, w2h, w2l, w1h, bnA, bnB, xh, xl);
  xprep<<<dim3(64, 8, 2), 256, 0, stream>>>(x, xh, xl);

  // ---- feat = relu(BN(wk @ x)): MODE0, 2 K-splits of 256
  {
    GemmArgs a = {};
    a.segs[0] = {wkh,       wkl,       xh,       xl,       0};
    a.segs[1] = {wkh + 256, wkl + 256, xh + 256, xl + 256, 0};
    a.nseg = 2; a.segs_per_split = 1; a.K = 256; a.ldA = 512; a.ldB = 512;
    a.sA = 0; a.sB = (long long)4356 * 512; a.alpha = 1.f;
    a.outf = big_part; a.sOut = (long long)4096 * 256; a.sSplit = FT_LL; a.ldT = 256;
    gemm_tn<64, 128, 0, true, false><<<dim3(32, 4, 4), 256, 0, stream>>>(a);
    reduce_split<256, true><<<2048, 256, 0, stream>>>(big_part, FT_LL, 2, bnA, bnB, fth, ftl, FT_LL);
  }
  // ---- QK: S = fth @ (fth+ftl)^T * Ck^-0.5, MODE1, symmetric upper-triangle
  {
    GemmArgs a = {};
    a.segs[0] = {fth, nullptr, fth, ftl, 0};
    a.nseg = 1; a.segs_per_split = 1; a.K = 256; a.ldA = 256; a.ldB = 256;
    a.sA = (long long)4096 * 256; a.sB = (long long)4096 * 256; a.alpha = 0.0625f;
    a.outf = sim; a.sOut = (long long)4096 * 4096; a.sSplit = 0; a.ldT = 4096;
    gemm_tn<128, 128, 1, false, true><<<dim3(528, 1, 2), 256, 0, stream>>>(a);
  }
  // ---- conv3x3 -> v1T partials: 3 ty-splits, tap-shared B staging
  {
    Conv3Args a;
    a.W = w1h; a.X = xh;
    a.outf = big_part; a.sOut = (long long)4096 * 256; a.sSplit = FT_LL;
    conv3_gemm<<<dim3(32, 2, 6), 256, 0, stream>>>(a);
    reduce_split<256, true><<<2048, 256, 0, stream>>>(big_part, FT_LL, 3, nullptr, bv1, v1h, v1l, FT_LL);
  }
  // ---- v = relu(wv2 @ v1 + bv2), flipped (M=4096, N=256), MODE0, 2 K-splits
  {
    GemmArgs a = {};
    a.segs[0] = {v1h,       v1l,       w2h,       w2l,       0};
    a.segs[1] = {v1h + 128, v1l + 128, w2h + 128, w2l + 128, 0};
    a.nseg = 2; a.segs_per_split = 1; a.K = 128; a.ldA = 256; a.ldB = 256;
    a.sA = (long long)4096 * 256; a.sB = 0; a.alpha = 1.f;
    a.outf = big_part; a.sOut = (long long)256 * 4096; a.sSplit = FT_LL; a.ldT = 4096;
    gemm_tn<128, 64, 0, false, false><<<dim3(4, 32, 4), 256, 0, stream>>>(a);
    reduce_split<4096, false><<<2048, 256, 0, stream>>>(big_part, FT_LL, 2, nullptr, bv2, vh, nullptr, FT_LL);
  }
  softmax_k<<<B * 4096, 256, 0, stream>>>(sim, Pb);
  // ---- ctx = P @ v^T: MODE2, NCH=8 (K_STEP 64), 4 K-splits of 1024
  {
    GemmArgs a = {};
    for (int q = 0; q < 4; ++q)
      a.segs[q] = {Pb + (size_t)q * 1024, nullptr, vh + (size_t)q * 1024, nullptr, 0};
    a.nseg = 4; a.segs_per_split = 1; a.K = 1024; a.ldA = 4096; a.ldB = 4096;
    a.sA = (long long)4096 * 4096; a.sB = (long long)256 * 4096; a.alpha = 1.f;
    a.outf = pv_part; a.sOut = (long long)256 * 4096; a.sSplit = FT_LL; a.ldT = 4096;
    gemm_tn<128, 128, 2, false, false, 8><<<dim3(2, 32, 8), 256, 0, stream>>>(a);
    reduce_split_f32<<<2048, 256, 0, stream>>>(pv_part, FT_LL, 4, ctx, FT_LL);
  }
}